// Round 1
// baseline (1698.540 us; speedup 1.0000x reference)
//
#include <hip/hip_runtime.h>
#include <hip/hip_bf16.h>

typedef __bf16 bf16t;
typedef bf16t bf16x4 __attribute__((ext_vector_type(4)));
typedef bf16t bf16x8 __attribute__((ext_vector_type(8)));
typedef float f32x4 __attribute__((ext_vector_type(4)));

#define BT 8192      // B*T rows
#define TT 1024      // T
#define DM 1024      // d_model
#define DFF 4096

static __device__ __forceinline__ f32x4 mfma16(bf16x8 a, bf16x8 b, f32x4 c) {
  return __builtin_amdgcn_mfma_f32_16x16x32_bf16(a, b, c, 0, 0, 0);
}
static __device__ __forceinline__ bf16x8 ld8(const bf16t* p0, const bf16t* p1) {
  bf16x4 lo = *(const bf16x4*)p0;
  bf16x4 hi = *(const bf16x4*)p1;
  return __builtin_shufflevector(lo, hi, 0, 1, 2, 3, 4, 5, 6, 7);
}
static __device__ __forceinline__ f32x4 f4zero() {
  f32x4 z = {0.f, 0.f, 0.f, 0.f};
  return z;
}

// ---------------- f32 -> bf16 convert ----------------
__global__ __launch_bounds__(256) void cvt_kernel(const float* __restrict__ in,
                                                  bf16t* __restrict__ out, long n) {
  long i = ((long)blockIdx.x * 256 + threadIdx.x) * 4;
  if (i >= n) return;
  f32x4 v = *(const f32x4*)&in[i];
  bf16x4 o = {(bf16t)v[0], (bf16t)v[1], (bf16t)v[2], (bf16t)v[3]};
  *(bf16x4*)&out[i] = o;
}

// ---------------- pack per-head Wq/Wk/Wv into [1024][3072] bf16 + bias ----------------
__global__ __launch_bounds__(256) void pack_qkv_kernel(
    const float* __restrict__ Wq, const float* __restrict__ Wk, const float* __restrict__ Wv,
    const float* __restrict__ bq, const float* __restrict__ bk, const float* __restrict__ bv,
    bf16t* __restrict__ Wqkv, float* __restrict__ bqkv) {
  long idx = (long)blockIdx.x * 256 + threadIdx.x;  // 1024*3072 total
  int d = (int)(idx / 3072), c = (int)(idx % 3072);
  int sel = c >> 10;
  int cc = c & 1023;
  int h = cc >> 6, kk = cc & 63;
  const float* W = (sel == 0) ? Wq : (sel == 1) ? Wk : Wv;
  Wqkv[idx] = (bf16t)W[((long)h << 16) + (d << 6) + kk];  // Wx[h][d][kk]
  if (idx < 3072) {
    int s2 = (int)(idx >> 10), c2 = (int)(idx & 1023);
    bqkv[idx] = ((s2 == 0) ? bq : (s2 == 1) ? bk : bv)[c2];
  }
}

// ---------------- GEMM: C[M,N] = A[M,K](bf16) * B[K,N](bf16) + epilogue ----------------
// EPI 0: bf16 out, +bias.  EPI 1: bf16 out, +bias, relu.  EPI 2: f32 out, +bias, +resid(f32).
template <int EPI>
__global__ __launch_bounds__(256) void gemm_kernel(
    const bf16t* __restrict__ A, const bf16t* __restrict__ Bm,
    const float* __restrict__ bias, const float* __restrict__ resid,
    void* __restrict__ Cout, int M, int N, int K) {
  __shared__ bf16t As[128][40];  // [row][k], pad 40 to spread banks
  __shared__ bf16t Bs[128][40];  // B^T tile: [col][k]
  const int tid = threadIdx.x;
  const int lane = tid & 63;
  const int wid = tid >> 6;
  const int wr = wid >> 1, wc = wid & 1;
  const int g = lane >> 4, lr = lane & 15;
  const long brow = (long)blockIdx.y * 128;
  const long bcol = (long)blockIdx.x * 128;

  f32x4 acc[4][4];
#pragma unroll
  for (int i = 0; i < 4; i++)
#pragma unroll
    for (int j = 0; j < 4; j++) acc[i][j] = f4zero();

  const int ar = tid >> 2;         // 0..63
  const int ac = (tid & 3) * 8;    // 0,8,16,24
  const int bkr = tid >> 5;        // 0..7
  const int bc4 = (tid & 31) * 4;  // 0..124

  for (int k0 = 0; k0 < K; k0 += 32) {
#pragma unroll
    for (int p = 0; p < 2; ++p) {
      int r = ar + p * 64;
      *(bf16x8*)&As[r][ac] = *(const bf16x8*)&A[(brow + r) * (long)K + k0 + ac];
    }
#pragma unroll
    for (int p = 0; p < 4; ++p) {
      int kr = bkr + p * 8;
      bf16x4 v = *(const bf16x4*)&Bm[(long)(k0 + kr) * N + bcol + bc4];
#pragma unroll
      for (int q = 0; q < 4; ++q) Bs[bc4 + q][kr] = v[q];
    }
    __syncthreads();

    bf16x8 af[4], bfv[4];
#pragma unroll
    for (int i = 0; i < 4; i++) {
      int r = wr * 64 + i * 16 + lr;
      af[i] = ld8(&As[r][4 * g], &As[r][16 + 4 * g]);
    }
#pragma unroll
    for (int j = 0; j < 4; j++) {
      int c = wc * 64 + j * 16 + lr;
      bfv[j] = ld8(&Bs[c][4 * g], &Bs[c][16 + 4 * g]);
    }
#pragma unroll
    for (int i = 0; i < 4; i++)
#pragma unroll
      for (int j = 0; j < 4; j++) acc[i][j] = mfma16(af[i], bfv[j], acc[i][j]);
    __syncthreads();
  }

#pragma unroll
  for (int j = 0; j < 4; j++) {
    int col = (int)bcol + wc * 64 + j * 16 + lr;
    float bval = bias ? bias[col] : 0.f;
#pragma unroll
    for (int i = 0; i < 4; i++) {
      long row0 = brow + wr * 64 + i * 16 + 4 * g;
#pragma unroll
      for (int r2 = 0; r2 < 4; r2++) {
        long row = row0 + r2;
        float v = acc[i][j][r2] + bval;
        if (EPI == 0) {
          ((bf16t*)Cout)[row * N + col] = (bf16t)v;
        } else if (EPI == 1) {
          ((bf16t*)Cout)[row * N + col] = (bf16t)fmaxf(v, 0.f);
        } else {
          ((float*)Cout)[row * N + col] = v + resid[row * N + col];
        }
      }
    }
  }
}

// ---------------- flash attention: qkv[M][3072] bf16 -> o[M][1024] bf16 ----------------
__global__ __launch_bounds__(256) void attn_kernel(const bf16t* __restrict__ qkv,
                                                   bf16t* __restrict__ o) {
  const int bh = blockIdx.x;  // 0..127
  const int b = bh >> 4, h = bh & 15;
  const int qt = blockIdx.y;  // 0..15
  const int tid = threadIdx.x;
  const int lane = tid & 63;
  const int w = tid >> 6;
  const int g = lane >> 4, lr = lane & 15;

  __shared__ bf16t Qs[64][72], Ks[64][72], Vt[64][72], Ps[64][72];

  const long rowbase = (long)b * TT;
  const long qrow0 = rowbase + (long)qt * 64;
  const int qoff = h * 64, koff = DM + h * 64, voff = 2 * DM + h * 64;

  {
    int r = tid >> 2, c = (tid & 3) * 16;
    const bf16t* src = &qkv[(qrow0 + r) * 3072 + qoff + c];
    *(bf16x8*)&Qs[r][c] = *(const bf16x8*)&src[0];
    *(bf16x8*)&Qs[r][c + 8] = *(const bf16x8*)&src[8];
  }
  __syncthreads();

  const int qr = w * 16 + lr;
  bf16x8 qa0 = ld8(&Qs[qr][4 * g], &Qs[qr][16 + 4 * g]);
  bf16x8 qa1 = ld8(&Qs[qr][32 + 4 * g], &Qs[qr][48 + 4 * g]);

  f32x4 acc_o[4];
#pragma unroll
  for (int j = 0; j < 4; j++) acc_o[j] = f4zero();
  float mrun[4], lrun[4];
#pragma unroll
  for (int r = 0; r < 4; r++) {
    mrun[r] = -1e30f;
    lrun[r] = 0.f;
  }

  for (int kt = 0; kt < 16; ++kt) {
    __syncthreads();  // previous tile's K/V reads done
    {
      int r = tid >> 2, c = (tid & 3) * 16;
      const bf16t* ksrc = &qkv[(rowbase + kt * 64 + r) * 3072 + koff + c];
      *(bf16x8*)&Ks[r][c] = *(const bf16x8*)&ksrc[0];
      *(bf16x8*)&Ks[r][c + 8] = *(const bf16x8*)&ksrc[8];
      const bf16t* vsrc = &qkv[(rowbase + kt * 64 + r) * 3072 + voff + c];
      bf16x8 v0 = *(const bf16x8*)&vsrc[0];
      bf16x8 v1 = *(const bf16x8*)&vsrc[8];
#pragma unroll
      for (int q2 = 0; q2 < 8; q2++) {
        Vt[c + q2][r] = v0[q2];
        Vt[c + 8 + q2][r] = v1[q2];
      }
    }
    __syncthreads();

    // S = Q K^T for this wave's 16 rows (4 col-tiles x K=64)
    f32x4 s[4];
#pragma unroll
    for (int jt = 0; jt < 4; jt++) {
      int jc = jt * 16 + lr;
      bf16x8 kb0 = ld8(&Ks[jc][4 * g], &Ks[jc][16 + 4 * g]);
      bf16x8 kb1 = ld8(&Ks[jc][32 + 4 * g], &Ks[jc][48 + 4 * g]);
      f32x4 t = f4zero();
      t = mfma16(qa0, kb0, t);
      t = mfma16(qa1, kb1, t);
      s[jt] = t;
    }

    // online softmax; lane holds rows 4g+r (r=reg), cols jt*16+lr
    float tm[4];
#pragma unroll
    for (int r = 0; r < 4; r++) tm[r] = -1e30f;
#pragma unroll
    for (int jt = 0; jt < 4; jt++)
#pragma unroll
      for (int r = 0; r < 4; r++) {
        float x = s[jt][r] * 0.125f;
        s[jt][r] = x;
        tm[r] = fmaxf(tm[r], x);
      }
#pragma unroll
    for (int m = 1; m < 16; m <<= 1)
#pragma unroll
      for (int r = 0; r < 4; r++) tm[r] = fmaxf(tm[r], __shfl_xor(tm[r], m, 64));

    float corr[4], tsum[4];
#pragma unroll
    for (int r = 0; r < 4; r++) {
      float mnew = fmaxf(mrun[r], tm[r]);
      corr[r] = __expf(mrun[r] - mnew);
      mrun[r] = mnew;
      tsum[r] = 0.f;
    }
#pragma unroll
    for (int jt = 0; jt < 4; jt++)
#pragma unroll
      for (int r = 0; r < 4; r++) {
        float pv = __expf(s[jt][r] - mrun[r]);
        s[jt][r] = pv;
        tsum[r] += pv;
      }
#pragma unroll
    for (int m = 1; m < 16; m <<= 1)
#pragma unroll
      for (int r = 0; r < 4; r++) tsum[r] += __shfl_xor(tsum[r], m, 64);
#pragma unroll
    for (int r = 0; r < 4; r++) lrun[r] = lrun[r] * corr[r] + tsum[r];
#pragma unroll
    for (int jt = 0; jt < 4; jt++)
#pragma unroll
      for (int r = 0; r < 4; r++) acc_o[jt][r] *= corr[r];

    // P -> LDS (bf16); rows are wave-private so no cross-wave barrier needed
#pragma unroll
    for (int jt = 0; jt < 4; jt++)
#pragma unroll
      for (int r = 0; r < 4; r++) Ps[w * 16 + 4 * g + r][jt * 16 + lr] = (bf16t)s[jt][r];

    const int pr = w * 16 + lr;
    bf16x8 pa0 = ld8(&Ps[pr][4 * g], &Ps[pr][16 + 4 * g]);
    bf16x8 pa1 = ld8(&Ps[pr][32 + 4 * g], &Ps[pr][48 + 4 * g]);
#pragma unroll
    for (int dt = 0; dt < 4; dt++) {
      int dc = dt * 16 + lr;
      bf16x8 vb0 = ld8(&Vt[dc][4 * g], &Vt[dc][16 + 4 * g]);
      bf16x8 vb1 = ld8(&Vt[dc][32 + 4 * g], &Vt[dc][48 + 4 * g]);
      acc_o[dt] = mfma16(pa0, vb0, acc_o[dt]);
      acc_o[dt] = mfma16(pa1, vb1, acc_o[dt]);
    }
  }

#pragma unroll
  for (int dt = 0; dt < 4; dt++) {
#pragma unroll
    for (int r = 0; r < 4; r++) {
      long row = qrow0 + w * 16 + 4 * g + r;
      o[row * (long)DM + h * 64 + dt * 16 + lr] = (bf16t)(acc_o[dt][r] / lrun[r]);
    }
  }
}

// ---------------- LayerNorm: x[row][1024] f32 -> bf16 out and/or f32 out ----------------
__global__ __launch_bounds__(256) void ln_kernel(const float* __restrict__ x,
                                                 const float* __restrict__ gamma,
                                                 const float* __restrict__ beta,
                                                 bf16t* __restrict__ out_bf,
                                                 float* __restrict__ out_f32) {
  const long row = blockIdx.x;
  const int tid = threadIdx.x;
  const float* xr = x + row * DM;
  f32x4 v = *(const f32x4*)&xr[tid * 4];
  float s = v[0] + v[1] + v[2] + v[3];
  float ss = v[0] * v[0] + v[1] * v[1] + v[2] * v[2] + v[3] * v[3];
#pragma unroll
  for (int m = 1; m < 64; m <<= 1) {
    s += __shfl_xor(s, m, 64);
    ss += __shfl_xor(ss, m, 64);
  }
  __shared__ float red[8];
  const int w = tid >> 6, lane = tid & 63;
  if (lane == 0) {
    red[w] = s;
    red[4 + w] = ss;
  }
  __syncthreads();
  s = red[0] + red[1] + red[2] + red[3];
  ss = red[4] + red[5] + red[6] + red[7];
  float mean = s * (1.f / DM);
  float var = ss * (1.f / DM) - mean * mean;
  float inv = rsqrtf(var + 1e-5f);
  f32x4 ga = *(const f32x4*)&gamma[tid * 4];
  f32x4 be = *(const f32x4*)&beta[tid * 4];
  bf16x4 ob;
  f32x4 of;
#pragma unroll
  for (int c = 0; c < 4; c++) {
    float y = (v[c] - mean) * inv * ga[c] + be[c];
    ob[c] = (bf16t)y;
    of[c] = y;
  }
  long base = row * DM + tid * 4;
  if (out_bf) *(bf16x4*)&out_bf[base] = ob;
  if (out_f32) *(f32x4*)&out_f32[base] = of;
}

extern "C" void kernel_launch(void* const* d_in, const int* in_sizes, int n_in,
                              void* d_out, int out_size, void* d_ws, size_t ws_size,
                              hipStream_t stream) {
  const float* z = (const float*)d_in[0];
  const float* Wq = (const float*)d_in[1];
  const float* bq = (const float*)d_in[2];
  const float* Wk = (const float*)d_in[3];
  const float* bk = (const float*)d_in[4];
  const float* Wv = (const float*)d_in[5];
  const float* bv = (const float*)d_in[6];
  const float* Wo = (const float*)d_in[7];
  const float* bo = (const float*)d_in[8];
  const float* W1 = (const float*)d_in[9];
  const float* b1 = (const float*)d_in[10];
  const float* W2 = (const float*)d_in[11];
  const float* b2 = (const float*)d_in[12];
  const float* g1 = (const float*)d_in[13];
  const float* be1 = (const float*)d_in[14];
  const float* g2 = (const float*)d_in[15];
  const float* be2 = (const float*)d_in[16];

  char* p = (char*)d_ws;
  auto alloc = [&](size_t bytes) {
    char* r = p;
    p += (bytes + 255) & ~(size_t)255;
    return r;
  };
  bf16t* wqkv = (bf16t*)alloc((size_t)1024 * 3072 * 2);
  float* bqkv = (float*)alloc((size_t)3072 * 4);
  bf16t* wo = (bf16t*)alloc((size_t)1024 * 1024 * 2);
  bf16t* w1 = (bf16t*)alloc((size_t)1024 * 4096 * 2);
  bf16t* w2 = (bf16t*)alloc((size_t)4096 * 1024 * 2);
  bf16t* act = (bf16t*)alloc((size_t)BT * 1024 * 2);
  bf16t* obuf = (bf16t*)alloc((size_t)BT * 1024 * 2);
  bf16t* big = (bf16t*)alloc((size_t)BT * 4096 * 2);  // qkv[M][3072] and ffn-h[M][4096] share
  float* tbuf = (float*)alloc((size_t)BT * 1024 * 4);
  float* residf = (float*)alloc((size_t)BT * 1024 * 4);

  pack_qkv_kernel<<<dim3(12288), dim3(256), 0, stream>>>(Wq, Wk, Wv, bq, bk, bv, wqkv, bqkv);
  cvt_kernel<<<dim3(1024), dim3(256), 0, stream>>>(Wo, wo, (long)1024 * 1024);
  cvt_kernel<<<dim3(4096), dim3(256), 0, stream>>>(W1, w1, (long)1024 * 4096);
  cvt_kernel<<<dim3(4096), dim3(256), 0, stream>>>(W2, w2, (long)4096 * 1024);
  cvt_kernel<<<dim3(8192), dim3(256), 0, stream>>>(z, act, (long)BT * 1024);

  for (int iter = 0; iter < 2; ++iter) {
    // QKV projection
    gemm_kernel<0><<<dim3(24, 64), dim3(256), 0, stream>>>(
        act, wqkv, bqkv, (const float*)nullptr, (void*)big, BT, 3072, 1024);
    // attention
    attn_kernel<<<dim3(128, 16), dim3(256), 0, stream>>>(big, obuf);
    // O-projection + residual
    const float* rsrc = (iter == 0) ? z : residf;
    gemm_kernel<2><<<dim3(8, 64), dim3(256), 0, stream>>>(
        obuf, wo, bo, rsrc, (void*)tbuf, BT, 1024, 1024);
    if (iter == 1) {
      // final LN1 -> d_out (f32); z_refined is LN1 output of last iteration
      ln_kernel<<<dim3(8192), dim3(256), 0, stream>>>(tbuf, g1, be1, (bf16t*)nullptr,
                                                      (float*)d_out);
      break;
    }
    ln_kernel<<<dim3(8192), dim3(256), 0, stream>>>(tbuf, g1, be1, act, residf);
    // FFN
    gemm_kernel<1><<<dim3(32, 64), dim3(256), 0, stream>>>(
        act, w1, b1, (const float*)nullptr, (void*)big, BT, 4096, 1024);
    gemm_kernel<2><<<dim3(8, 64), dim3(256), 0, stream>>>(
        big, w2, b2, residf, (void*)tbuf, BT, 1024, 4096);
    ln_kernel<<<dim3(8192), dim3(256), 0, stream>>>(tbuf, g2, be2, act, residf);
  }
}

// Round 2
// 1435.399 us; speedup vs baseline: 1.1833x; 1.1833x over previous
//
#include <hip/hip_runtime.h>
#include <hip/hip_bf16.h>

typedef __bf16 bf16t;
typedef bf16t bf16x4 __attribute__((ext_vector_type(4)));
typedef bf16t bf16x8 __attribute__((ext_vector_type(8)));
typedef float f32x4 __attribute__((ext_vector_type(4)));

#define BT 8192      // B*T rows
#define TT 1024      // T
#define DM 1024      // d_model
#define DFF 4096

static __device__ __forceinline__ f32x4 mfma16(bf16x8 a, bf16x8 b, f32x4 c) {
  return __builtin_amdgcn_mfma_f32_16x16x32_bf16(a, b, c, 0, 0, 0);
}
static __device__ __forceinline__ bf16x8 ld8(const bf16t* p0, const bf16t* p1) {
  bf16x4 lo = *(const bf16x4*)p0;
  bf16x4 hi = *(const bf16x4*)p1;
  return __builtin_shufflevector(lo, hi, 0, 1, 2, 3, 4, 5, 6, 7);
}
static __device__ __forceinline__ f32x4 f4zero() {
  f32x4 z = {0.f, 0.f, 0.f, 0.f};
  return z;
}
// async global->LDS, 16 bytes per lane; lds dest = wave-uniform base + lane*16
static __device__ __forceinline__ void gld16(const bf16t* g, bf16t* l) {
  __builtin_amdgcn_global_load_lds((const __attribute__((address_space(1))) void*)g,
                                   (__attribute__((address_space(3))) void*)l, 16, 0, 0);
}

// ---------------- f32 -> bf16 convert (no transpose) ----------------
__global__ __launch_bounds__(256) void cvt_kernel(const float* __restrict__ in,
                                                  bf16t* __restrict__ out, long n) {
  long i = ((long)blockIdx.x * 256 + threadIdx.x) * 4;
  if (i >= n) return;
  f32x4 v = *(const f32x4*)&in[i];
  bf16x4 o = {(bf16t)v[0], (bf16t)v[1], (bf16t)v[2], (bf16t)v[3]};
  *(bf16x4*)&out[i] = o;
}

// ---------------- transpose-convert: out[N][M] = (bf16) in[M][N], 64x64 LDS tiles ----------------
__global__ __launch_bounds__(256) void tcvt_kernel(const float* __restrict__ in,
                                                   bf16t* __restrict__ out, int M, int N) {
  __shared__ float T[64][65];
  const int t = threadIdx.x;
  const int ty = t >> 6, tx = t & 63;
  const long n0 = (long)blockIdx.x * 64, m0 = (long)blockIdx.y * 64;
#pragma unroll
  for (int p = 0; p < 16; ++p) {
    int a = ty * 16 + p;
    T[a][tx] = in[(m0 + a) * N + n0 + tx];
  }
  __syncthreads();
#pragma unroll
  for (int p = 0; p < 16; ++p) {
    int r = ty * 16 + p;
    out[(n0 + r) * M + m0 + tx] = (bf16t)T[tx][r];
  }
}

// ---------------- pack Wq/Wk/Wv [H][D][Dh] -> transposed [3072][1024] bf16 ----------------
__global__ __launch_bounds__(256) void pack_qkv_t_kernel(const float* __restrict__ Wq,
                                                         const float* __restrict__ Wk,
                                                         const float* __restrict__ Wv,
                                                         bf16t* __restrict__ WT) {
  __shared__ float T[64][65];
  const int bx = blockIdx.x;  // 0..47 : sel*16 + h
  const int sel = bx >> 4, h = bx & 15;
  const float* src = ((sel == 0) ? Wq : (sel == 1) ? Wk : Wv) + (long)h * 65536;  // [1024][64]
  const long nbase = (long)sel * 1024 + h * 64;
  const long m0 = (long)blockIdx.y * 64;  // d tile
  const int t = threadIdx.x;
  const int ty = t >> 6, tx = t & 63;
#pragma unroll
  for (int p = 0; p < 16; ++p) {
    int a = ty * 16 + p;
    T[a][tx] = src[(m0 + a) * 64 + tx];  // [d_local][kk]
  }
  __syncthreads();
#pragma unroll
  for (int p = 0; p < 16; ++p) {
    int r = ty * 16 + p;  // kk
    WT[(nbase + r) * 1024 + m0 + tx] = (bf16t)T[tx][r];
  }
}

__global__ __launch_bounds__(256) void pack_bias_kernel(const float* __restrict__ bq,
                                                        const float* __restrict__ bk,
                                                        const float* __restrict__ bv,
                                                        float* __restrict__ bqkv) {
  int i = blockIdx.x * 256 + threadIdx.x;
  if (i >= 3072) return;
  int sel = i >> 10, c = i & 1023;
  bqkv[i] = ((sel == 0) ? bq : (sel == 1) ? bk : bv)[c];
}

// ---------------- GEMM: C[M,N] = A[M,K](bf16) * B^T  where Bt is [N][K](bf16) ----------------
// m97 structure: 128x128 tile, BK=32, global_load_lds staging, 2 barriers/K-step.
// EPI 0: bf16 out, +bias.  EPI 1: bf16 out, +bias, relu.  EPI 2: f32 out, +bias, +resid(f32).
template <int EPI>
__global__ __launch_bounds__(256) void gemm_kernel(
    const bf16t* __restrict__ A, const bf16t* __restrict__ Bt,
    const float* __restrict__ bias, const float* __restrict__ resid,
    void* __restrict__ Cout, int M, int N, int K) {
  __shared__ bf16t As[128 * 32];
  __shared__ bf16t Bs[128 * 32];
  const int tid = threadIdx.x;
  const int lane = tid & 63;
  const int wid = tid >> 6;
  const int wr = wid >> 1, wc = wid & 1;
  const int g = lane >> 4, lr = lane & 15;
  const long brow = (long)blockIdx.y * 128;
  const long bcol = (long)blockIdx.x * 128;

  f32x4 acc[4][4];
#pragma unroll
  for (int i = 0; i < 4; i++)
#pragma unroll
    for (int j = 0; j < 4; j++) acc[i][j] = f4zero();

  // staging: thread t covers LDS bytes t*16 of each 4KB round; 2 rounds per matrix
  const int srow = tid >> 2;       // 0..63 row within round
  const int sk8 = (tid & 3) * 8;   // k elems 0,8,16,24
  const bf16t* gA = &A[(brow + srow) * (long)K + sk8];
  const bf16t* gB = &Bt[(bcol + srow) * (long)K + sk8];
  bf16t* lA = As + wid * 512;  // wave-uniform base (bytes: wid*1024)
  bf16t* lB = Bs + wid * 512;

  for (int k0 = 0; k0 < K; k0 += 32) {
    gld16(gA + k0, lA);
    gld16(gA + k0 + (long)64 * K, lA + 2048);
    gld16(gB + k0, lB);
    gld16(gB + k0 + (long)64 * K, lB + 2048);
    __syncthreads();  // drains vmcnt(0) before barrier

    bf16x8 af[4], bfv[4];
#pragma unroll
    for (int i = 0; i < 4; i++) {
      const bf16t* r = As + (wr * 64 + i * 16 + lr) * 32;
      af[i] = ld8(r + 4 * g, r + 16 + 4 * g);
    }
#pragma unroll
    for (int j = 0; j < 4; j++) {
      const bf16t* c = Bs + (wc * 64 + j * 16 + lr) * 32;
      bfv[j] = ld8(c + 4 * g, c + 16 + 4 * g);
    }
#pragma unroll
    for (int i = 0; i < 4; i++)
#pragma unroll
      for (int j = 0; j < 4; j++) acc[i][j] = mfma16(af[i], bfv[j], acc[i][j]);
    __syncthreads();  // LDS reads done before next stage overwrites
  }

#pragma unroll
  for (int j = 0; j < 4; j++) {
    int col = (int)bcol + wc * 64 + j * 16 + lr;
    float bval = bias ? bias[col] : 0.f;
#pragma unroll
    for (int i = 0; i < 4; i++) {
      long row0 = brow + wr * 64 + i * 16 + 4 * g;
#pragma unroll
      for (int r2 = 0; r2 < 4; r2++) {
        long row = row0 + r2;
        float v = acc[i][j][r2] + bval;
        if (EPI == 0) {
          ((bf16t*)Cout)[row * N + col] = (bf16t)v;
        } else if (EPI == 1) {
          ((bf16t*)Cout)[row * N + col] = (bf16t)fmaxf(v, 0.f);
        } else {
          ((float*)Cout)[row * N + col] = v + resid[row * N + col];
        }
      }
    }
  }
}

// ---------------- flash attention: qkv[M][3072] bf16 -> o[M][1024] bf16 ----------------
__global__ __launch_bounds__(256) void attn_kernel(const bf16t* __restrict__ qkv,
                                                   bf16t* __restrict__ o) {
  const int bh = blockIdx.x;  // 0..127
  const int b = bh >> 4, h = bh & 15;
  const int qt = blockIdx.y;  // 0..15
  const int tid = threadIdx.x;
  const int lane = tid & 63;
  const int w = tid >> 6;
  const int g = lane >> 4, lr = lane & 15;

  __shared__ bf16t Qs[64][72], Ks[64][72], Vt[64][72], Ps[64][72];

  const long rowbase = (long)b * TT;
  const long qrow0 = rowbase + (long)qt * 64;
  const int qoff = h * 64, koff = DM + h * 64, voff = 2 * DM + h * 64;

  {
    int r = tid >> 2, c = (tid & 3) * 16;
    const bf16t* src = &qkv[(qrow0 + r) * 3072 + qoff + c];
    *(bf16x8*)&Qs[r][c] = *(const bf16x8*)&src[0];
    *(bf16x8*)&Qs[r][c + 8] = *(const bf16x8*)&src[8];
  }
  __syncthreads();

  const int qr = w * 16 + lr;
  bf16x8 qa0 = ld8(&Qs[qr][4 * g], &Qs[qr][16 + 4 * g]);
  bf16x8 qa1 = ld8(&Qs[qr][32 + 4 * g], &Qs[qr][48 + 4 * g]);

  f32x4 acc_o[4];
#pragma unroll
  for (int j = 0; j < 4; j++) acc_o[j] = f4zero();
  float mrun[4], lrun[4];
#pragma unroll
  for (int r = 0; r < 4; r++) {
    mrun[r] = -1e30f;
    lrun[r] = 0.f;
  }

  for (int kt = 0; kt < 16; ++kt) {
    __syncthreads();  // previous tile's K/V reads done
    {
      int r = tid >> 2, c = (tid & 3) * 16;
      const bf16t* ksrc = &qkv[(rowbase + kt * 64 + r) * 3072 + koff + c];
      *(bf16x8*)&Ks[r][c] = *(const bf16x8*)&ksrc[0];
      *(bf16x8*)&Ks[r][c + 8] = *(const bf16x8*)&ksrc[8];
      const bf16t* vsrc = &qkv[(rowbase + kt * 64 + r) * 3072 + voff + c];
      bf16x8 v0 = *(const bf16x8*)&vsrc[0];
      bf16x8 v1 = *(const bf16x8*)&vsrc[8];
#pragma unroll
      for (int q2 = 0; q2 < 8; q2++) {
        Vt[c + q2][r] = v0[q2];
        Vt[c + 8 + q2][r] = v1[q2];
      }
    }
    __syncthreads();

    // S = Q K^T for this wave's 16 rows (4 col-tiles x K=64)
    f32x4 s[4];
#pragma unroll
    for (int jt = 0; jt < 4; jt++) {
      int jc = jt * 16 + lr;
      bf16x8 kb0 = ld8(&Ks[jc][4 * g], &Ks[jc][16 + 4 * g]);
      bf16x8 kb1 = ld8(&Ks[jc][32 + 4 * g], &Ks[jc][48 + 4 * g]);
      f32x4 t = f4zero();
      t = mfma16(qa0, kb0, t);
      t = mfma16(qa1, kb1, t);
      s[jt] = t;
    }

    // online softmax; lane holds rows 4g+r (r=reg), cols jt*16+lr
    float tm[4];
#pragma unroll
    for (int r = 0; r < 4; r++) tm[r] = -1e30f;
#pragma unroll
    for (int jt = 0; jt < 4; jt++)
#pragma unroll
      for (int r = 0; r < 4; r++) {
        float x = s[jt][r] * 0.125f;
        s[jt][r] = x;
        tm[r] = fmaxf(tm[r], x);
      }
#pragma unroll
    for (int m = 1; m < 16; m <<= 1)
#pragma unroll
      for (int r = 0; r < 4; r++) tm[r] = fmaxf(tm[r], __shfl_xor(tm[r], m, 64));

    float corr[4], tsum[4];
#pragma unroll
    for (int r = 0; r < 4; r++) {
      float mnew = fmaxf(mrun[r], tm[r]);
      corr[r] = __expf(mrun[r] - mnew);
      mrun[r] = mnew;
      tsum[r] = 0.f;
    }
#pragma unroll
    for (int jt = 0; jt < 4; jt++)
#pragma unroll
      for (int r = 0; r < 4; r++) {
        float pv = __expf(s[jt][r] - mrun[r]);
        s[jt][r] = pv;
        tsum[r] += pv;
      }
#pragma unroll
    for (int m = 1; m < 16; m <<= 1)
#pragma unroll
      for (int r = 0; r < 4; r++) tsum[r] += __shfl_xor(tsum[r], m, 64);
#pragma unroll
    for (int r = 0; r < 4; r++) lrun[r] = lrun[r] * corr[r] + tsum[r];
#pragma unroll
    for (int jt = 0; jt < 4; jt++)
#pragma unroll
      for (int r = 0; r < 4; r++) acc_o[jt][r] *= corr[r];

    // P -> LDS (bf16); rows are wave-private so no cross-wave barrier needed
#pragma unroll
    for (int jt = 0; jt < 4; jt++)
#pragma unroll
      for (int r = 0; r < 4; r++) Ps[w * 16 + 4 * g + r][jt * 16 + lr] = (bf16t)s[jt][r];

    const int pr = w * 16 + lr;
    bf16x8 pa0 = ld8(&Ps[pr][4 * g], &Ps[pr][16 + 4 * g]);
    bf16x8 pa1 = ld8(&Ps[pr][32 + 4 * g], &Ps[pr][48 + 4 * g]);
#pragma unroll
    for (int dt = 0; dt < 4; dt++) {
      int dc = dt * 16 + lr;
      bf16x8 vb0 = ld8(&Vt[dc][4 * g], &Vt[dc][16 + 4 * g]);
      bf16x8 vb1 = ld8(&Vt[dc][32 + 4 * g], &Vt[dc][48 + 4 * g]);
      acc_o[dt] = mfma16(pa0, vb0, acc_o[dt]);
      acc_o[dt] = mfma16(pa1, vb1, acc_o[dt]);
    }
  }

#pragma unroll
  for (int dt = 0; dt < 4; dt++) {
#pragma unroll
    for (int r = 0; r < 4; r++) {
      long row = qrow0 + w * 16 + 4 * g + r;
      o[row * (long)DM + h * 64 + dt * 16 + lr] = (bf16t)(acc_o[dt][r] / lrun[r]);
    }
  }
}

// ---------------- LayerNorm: x[row][1024] f32 -> bf16 out and/or f32 out ----------------
__global__ __launch_bounds__(256) void ln_kernel(const float* __restrict__ x,
                                                 const float* __restrict__ gamma,
                                                 const float* __restrict__ beta,
                                                 bf16t* __restrict__ out_bf,
                                                 float* __restrict__ out_f32) {
  const long row = blockIdx.x;
  const int tid = threadIdx.x;
  const float* xr = x + row * DM;
  f32x4 v = *(const f32x4*)&xr[tid * 4];
  float s = v[0] + v[1] + v[2] + v[3];
  float ss = v[0] * v[0] + v[1] * v[1] + v[2] * v[2] + v[3] * v[3];
#pragma unroll
  for (int m = 1; m < 64; m <<= 1) {
    s += __shfl_xor(s, m, 64);
    ss += __shfl_xor(ss, m, 64);
  }
  __shared__ float red[8];
  const int w = tid >> 6, lane = tid & 63;
  if (lane == 0) {
    red[w] = s;
    red[4 + w] = ss;
  }
  __syncthreads();
  s = red[0] + red[1] + red[2] + red[3];
  ss = red[4] + red[5] + red[6] + red[7];
  float mean = s * (1.f / DM);
  float var = ss * (1.f / DM) - mean * mean;
  float inv = rsqrtf(var + 1e-5f);
  f32x4 ga = *(const f32x4*)&gamma[tid * 4];
  f32x4 be = *(const f32x4*)&beta[tid * 4];
  bf16x4 ob;
  f32x4 of;
#pragma unroll
  for (int c = 0; c < 4; c++) {
    float y = (v[c] - mean) * inv * ga[c] + be[c];
    ob[c] = (bf16t)y;
    of[c] = y;
  }
  long base = row * DM + tid * 4;
  if (out_bf) *(bf16x4*)&out_bf[base] = ob;
  if (out_f32) *(f32x4*)&out_f32[base] = of;
}

extern "C" void kernel_launch(void* const* d_in, const int* in_sizes, int n_in,
                              void* d_out, int out_size, void* d_ws, size_t ws_size,
                              hipStream_t stream) {
  const float* z = (const float*)d_in[0];
  const float* Wq = (const float*)d_in[1];
  const float* bq = (const float*)d_in[2];
  const float* Wk = (const float*)d_in[3];
  const float* bk = (const float*)d_in[4];
  const float* Wv = (const float*)d_in[5];
  const float* bv = (const float*)d_in[6];
  const float* Wo = (const float*)d_in[7];
  const float* bo = (const float*)d_in[8];
  const float* W1 = (const float*)d_in[9];
  const float* b1 = (const float*)d_in[10];
  const float* W2 = (const float*)d_in[11];
  const float* b2 = (const float*)d_in[12];
  const float* g1 = (const float*)d_in[13];
  const float* be1 = (const float*)d_in[14];
  const float* g2 = (const float*)d_in[15];
  const float* be2 = (const float*)d_in[16];

  char* p = (char*)d_ws;
  auto alloc = [&](size_t bytes) {
    char* r = p;
    p += (bytes + 255) & ~(size_t)255;
    return r;
  };
  bf16t* wqkvT = (bf16t*)alloc((size_t)3072 * 1024 * 2);  // [3072][1024]
  float* bqkv = (float*)alloc((size_t)3072 * 4);
  bf16t* woT = (bf16t*)alloc((size_t)1024 * 1024 * 2);    // [1024][1024]
  bf16t* w1T = (bf16t*)alloc((size_t)4096 * 1024 * 2);    // [4096][1024]
  bf16t* w2T = (bf16t*)alloc((size_t)1024 * 4096 * 2);    // [1024][4096]
  bf16t* act = (bf16t*)alloc((size_t)BT * 1024 * 2);
  bf16t* obuf = (bf16t*)alloc((size_t)BT * 1024 * 2);
  bf16t* big = (bf16t*)alloc((size_t)BT * 4096 * 2);  // qkv[M][3072] and ffn-h[M][4096] share
  float* tbuf = (float*)alloc((size_t)BT * 1024 * 4);
  float* residf = (float*)alloc((size_t)BT * 1024 * 4);

  pack_qkv_t_kernel<<<dim3(48, 16), dim3(256), 0, stream>>>(Wq, Wk, Wv, wqkvT);
  pack_bias_kernel<<<dim3(12), dim3(256), 0, stream>>>(bq, bk, bv, bqkv);
  tcvt_kernel<<<dim3(16, 16), dim3(256), 0, stream>>>(Wo, woT, 1024, 1024);
  tcvt_kernel<<<dim3(64, 16), dim3(256), 0, stream>>>(W1, w1T, 1024, 4096);
  tcvt_kernel<<<dim3(16, 64), dim3(256), 0, stream>>>(W2, w2T, 4096, 1024);
  cvt_kernel<<<dim3(8192), dim3(256), 0, stream>>>(z, act, (long)BT * 1024);

  for (int iter = 0; iter < 2; ++iter) {
    // QKV projection
    gemm_kernel<0><<<dim3(24, 64), dim3(256), 0, stream>>>(
        act, wqkvT, bqkv, (const float*)nullptr, (void*)big, BT, 3072, 1024);
    // attention
    attn_kernel<<<dim3(128, 16), dim3(256), 0, stream>>>(big, obuf);
    // O-projection + residual
    const float* rsrc = (iter == 0) ? z : residf;
    gemm_kernel<2><<<dim3(8, 64), dim3(256), 0, stream>>>(
        obuf, woT, bo, rsrc, (void*)tbuf, BT, 1024, 1024);
    if (iter == 1) {
      // final LN1 -> d_out (f32); z_refined is LN1 output of last iteration
      ln_kernel<<<dim3(8192), dim3(256), 0, stream>>>(tbuf, g1, be1, (bf16t*)nullptr,
                                                      (float*)d_out);
      break;
    }
    ln_kernel<<<dim3(8192), dim3(256), 0, stream>>>(tbuf, g1, be1, act, residf);
    // FFN
    gemm_kernel<1><<<dim3(32, 64), dim3(256), 0, stream>>>(
        act, w1T, b1, (const float*)nullptr, (void*)big, BT, 4096, 1024);
    gemm_kernel<2><<<dim3(8, 64), dim3(256), 0, stream>>>(
        big, w2T, b2, residf, (void*)tbuf, BT, 1024, 4096);
    ln_kernel<<<dim3(8192), dim3(256), 0, stream>>>(tbuf, g2, be2, act, residf);
  }
}

// Round 3
// 828.284 us; speedup vs baseline: 2.0507x; 1.7330x over previous
//
#include <hip/hip_runtime.h>
#include <hip/hip_bf16.h>

typedef __bf16 bf16t;
typedef bf16t bf16x4 __attribute__((ext_vector_type(4)));
typedef bf16t bf16x8 __attribute__((ext_vector_type(8)));
typedef float f32x4 __attribute__((ext_vector_type(4)));

#define BT 8192      // B*T rows
#define TT 1024      // T
#define DM 1024      // d_model
#define DFF 4096

static __device__ __forceinline__ f32x4 mfma16(bf16x8 a, bf16x8 b, f32x4 c) {
  return __builtin_amdgcn_mfma_f32_16x16x32_bf16(a, b, c, 0, 0, 0);
}
static __device__ __forceinline__ bf16x8 ld8(const bf16t* p0, const bf16t* p1) {
  bf16x4 lo = *(const bf16x4*)p0;
  bf16x4 hi = *(const bf16x4*)p1;
  return __builtin_shufflevector(lo, hi, 0, 1, 2, 3, 4, 5, 6, 7);
}
static __device__ __forceinline__ f32x4 f4zero() {
  f32x4 z = {0.f, 0.f, 0.f, 0.f};
  return z;
}
// async global->LDS, 16 bytes per lane; lds dest = wave-uniform base + lane*16
static __device__ __forceinline__ void gld16(const bf16t* g, bf16t* l) {
  __builtin_amdgcn_global_load_lds((const __attribute__((address_space(1))) void*)g,
                                   (__attribute__((address_space(3))) void*)l, 16, 0, 0);
}

// ---------------- f32 -> bf16 convert (no transpose) ----------------
__global__ __launch_bounds__(256) void cvt_kernel(const float* __restrict__ in,
                                                  bf16t* __restrict__ out, long n) {
  long i = ((long)blockIdx.x * 256 + threadIdx.x) * 4;
  if (i >= n) return;
  f32x4 v = *(const f32x4*)&in[i];
  bf16x4 o = {(bf16t)v[0], (bf16t)v[1], (bf16t)v[2], (bf16t)v[3]};
  *(bf16x4*)&out[i] = o;
}

// ---------------- transpose-convert: out[N][M] = (bf16) in[M][N], 64x64 LDS tiles ----------------
__global__ __launch_bounds__(256) void tcvt_kernel(const float* __restrict__ in,
                                                   bf16t* __restrict__ out, int M, int N) {
  __shared__ float T[64][65];
  const int t = threadIdx.x;
  const int ty = t >> 6, tx = t & 63;
  const long n0 = (long)blockIdx.x * 64, m0 = (long)blockIdx.y * 64;
#pragma unroll
  for (int p = 0; p < 16; ++p) {
    int a = ty * 16 + p;
    T[a][tx] = in[(m0 + a) * N + n0 + tx];
  }
  __syncthreads();
#pragma unroll
  for (int p = 0; p < 16; ++p) {
    int r = ty * 16 + p;
    out[(n0 + r) * M + m0 + tx] = (bf16t)T[tx][r];
  }
}

// ---------------- pack Wq/Wk/Wv [H][D][Dh] -> transposed [3072][1024] bf16 ----------------
__global__ __launch_bounds__(256) void pack_qkv_t_kernel(const float* __restrict__ Wq,
                                                         const float* __restrict__ Wk,
                                                         const float* __restrict__ Wv,
                                                         bf16t* __restrict__ WT) {
  __shared__ float T[64][65];
  const int bx = blockIdx.x;  // 0..47 : sel*16 + h
  const int sel = bx >> 4, h = bx & 15;
  const float* src = ((sel == 0) ? Wq : (sel == 1) ? Wk : Wv) + (long)h * 65536;  // [1024][64]
  const long nbase = (long)sel * 1024 + h * 64;
  const long m0 = (long)blockIdx.y * 64;  // d tile
  const int t = threadIdx.x;
  const int ty = t >> 6, tx = t & 63;
#pragma unroll
  for (int p = 0; p < 16; ++p) {
    int a = ty * 16 + p;
    T[a][tx] = src[(m0 + a) * 64 + tx];  // [d_local][kk]
  }
  __syncthreads();
#pragma unroll
  for (int p = 0; p < 16; ++p) {
    int r = ty * 16 + p;  // kk
    WT[(nbase + r) * 1024 + m0 + tx] = (bf16t)T[tx][r];
  }
}

__global__ __launch_bounds__(256) void pack_bias_kernel(const float* __restrict__ bq,
                                                        const float* __restrict__ bk,
                                                        const float* __restrict__ bv,
                                                        float* __restrict__ bqkv) {
  int i = blockIdx.x * 256 + threadIdx.x;
  if (i >= 3072) return;
  int sel = i >> 10, c = i & 1023;
  bqkv[i] = ((sel == 0) ? bq : (sel == 1) ? bk : bv)[c];
}

// ---------------- GEMM: C[M,N] = A[M,K](bf16) * B^T  where Bt is [N][K](bf16) ----------------
// 128x128 tile, BK=32, global_load_lds staging, XOR-swizzled LDS (T2, both-sides),
// 2-phase double-buffer (T3-minimal), 1 barrier per K-step.
// LDS logical tile [128 rows][32 k] bf16; physical byte = logical ^ (((row>>1)&3)<<4).
// EPI 0: bf16 out, +bias.  EPI 1: bf16 out, +bias, relu.  EPI 2: f32 out, +bias, +resid(f32).
template <int EPI>
__global__ __launch_bounds__(256) void gemm_kernel(
    const bf16t* __restrict__ A, const bf16t* __restrict__ Bt,
    const float* __restrict__ bias, const float* __restrict__ resid,
    void* __restrict__ Cout, int M, int N, int K) {
  __shared__ bf16t As[2 * 128 * 32];
  __shared__ bf16t Bs[2 * 128 * 32];
  const int tid = threadIdx.x;
  const int lane = tid & 63;
  const int wid = tid >> 6;
  const int wr = wid >> 1, wc = wid & 1;
  const int g = lane >> 4, lr = lane & 15;
  const long brow = (long)blockIdx.y * 128;
  const long bcol = (long)blockIdx.x * 128;

  f32x4 acc[4][4];
#pragma unroll
  for (int i = 0; i < 4; i++)
#pragma unroll
    for (int j = 0; j < 4; j++) acc[i][j] = f4zero();

  // staging: thread t fills LDS row (t>>2), 16-byte chunk (t&3) [linear dest].
  // Swizzle: LDS (row R, chunk j) must hold global chunk j ^ ((R>>1)&3).
  const int srow = tid >> 2;                       // 0..63 row within round
  const int csrc = (tid & 3) ^ ((tid >> 3) & 3);   // pre-swizzled global 16B-chunk
  const bf16t* gA = &A[(brow + srow) * (long)K + 8 * csrc];
  const bf16t* gB = &Bt[(bcol + srow) * (long)K + 8 * csrc];
  bf16t* lA = As + wid * 512;  // wave-uniform base (bytes: wid*1024)
  bf16t* lB = Bs + wid * 512;

  // read-side swizzle: elem offset ^= ((lr>>1)&3)<<3
  const int xsw = ((lr >> 1) & 3) << 3;
  const int ra0 = (4 * g) ^ xsw;         // k-half 0 granule
  const int ra1 = (16 + 4 * g) ^ xsw;    // k-half 1 granule

  auto stage = [&](int buf, int k0) {
    gld16(gA + k0, lA + buf * 4096);
    gld16(gA + k0 + (long)64 * K, lA + buf * 4096 + 2048);
    gld16(gB + k0, lB + buf * 4096);
    gld16(gB + k0 + (long)64 * K, lB + buf * 4096 + 2048);
  };

  stage(0, 0);
  __syncthreads();  // drains vmcnt(0): buf0 ready

  int cur = 0;
  for (int k0 = 32; k0 < K; k0 += 32) {
    stage(cur ^ 1, k0);  // issue next tile's loads (latency hides under compute)

    bf16x8 af[4], bfv[4];
#pragma unroll
    for (int i = 0; i < 4; i++) {
      const bf16t* r = As + cur * 4096 + (wr * 64 + i * 16 + lr) * 32;
      af[i] = ld8(r + ra0, r + ra1);
    }
#pragma unroll
    for (int j = 0; j < 4; j++) {
      const bf16t* c = Bs + cur * 4096 + (wc * 64 + j * 16 + lr) * 32;
      bfv[j] = ld8(c + ra0, c + ra1);
    }
#pragma unroll
    for (int i = 0; i < 4; i++)
#pragma unroll
      for (int j = 0; j < 4; j++) acc[i][j] = mfma16(af[i], bfv[j], acc[i][j]);

    __syncthreads();  // drains vmcnt(0) (next buf ready) + guards buf reuse
    cur ^= 1;
  }
  {  // final tile (already resident)
    bf16x8 af[4], bfv[4];
#pragma unroll
    for (int i = 0; i < 4; i++) {
      const bf16t* r = As + cur * 4096 + (wr * 64 + i * 16 + lr) * 32;
      af[i] = ld8(r + ra0, r + ra1);
    }
#pragma unroll
    for (int j = 0; j < 4; j++) {
      const bf16t* c = Bs + cur * 4096 + (wc * 64 + j * 16 + lr) * 32;
      bfv[j] = ld8(c + ra0, c + ra1);
    }
#pragma unroll
    for (int i = 0; i < 4; i++)
#pragma unroll
      for (int j = 0; j < 4; j++) acc[i][j] = mfma16(af[i], bfv[j], acc[i][j]);
  }

#pragma unroll
  for (int j = 0; j < 4; j++) {
    int col = (int)bcol + wc * 64 + j * 16 + lr;
    float bval = bias ? bias[col] : 0.f;
#pragma unroll
    for (int i = 0; i < 4; i++) {
      long row0 = brow + wr * 64 + i * 16 + 4 * g;
#pragma unroll
      for (int r2 = 0; r2 < 4; r2++) {
        long row = row0 + r2;
        float v = acc[i][j][r2] + bval;
        if (EPI == 0) {
          ((bf16t*)Cout)[row * N + col] = (bf16t)v;
        } else if (EPI == 1) {
          ((bf16t*)Cout)[row * N + col] = (bf16t)fmaxf(v, 0.f);
        } else {
          ((float*)Cout)[row * N + col] = v + resid[row * N + col];
        }
      }
    }
  }
}

// ---------------- flash attention: qkv[M][3072] bf16 -> o[M][1024] bf16 ----------------
__global__ __launch_bounds__(256) void attn_kernel(const bf16t* __restrict__ qkv,
                                                   bf16t* __restrict__ o) {
  const int bh = blockIdx.x;  // 0..127
  const int b = bh >> 4, h = bh & 15;
  const int qt = blockIdx.y;  // 0..15
  const int tid = threadIdx.x;
  const int lane = tid & 63;
  const int w = tid >> 6;
  const int g = lane >> 4, lr = lane & 15;

  __shared__ bf16t Qs[64][72], Ks[64][72], Vt[64][72], Ps[64][72];

  const long rowbase = (long)b * TT;
  const long qrow0 = rowbase + (long)qt * 64;
  const int qoff = h * 64, koff = DM + h * 64, voff = 2 * DM + h * 64;

  {
    int r = tid >> 2, c = (tid & 3) * 16;
    const bf16t* src = &qkv[(qrow0 + r) * 3072 + qoff + c];
    *(bf16x8*)&Qs[r][c] = *(const bf16x8*)&src[0];
    *(bf16x8*)&Qs[r][c + 8] = *(const bf16x8*)&src[8];
  }
  __syncthreads();

  const int qr = w * 16 + lr;
  bf16x8 qa0 = ld8(&Qs[qr][4 * g], &Qs[qr][16 + 4 * g]);
  bf16x8 qa1 = ld8(&Qs[qr][32 + 4 * g], &Qs[qr][48 + 4 * g]);

  f32x4 acc_o[4];
#pragma unroll
  for (int j = 0; j < 4; j++) acc_o[j] = f4zero();
  float mrun[4], lrun[4];
#pragma unroll
  for (int r = 0; r < 4; r++) {
    mrun[r] = -1e30f;
    lrun[r] = 0.f;
  }

  for (int kt = 0; kt < 16; ++kt) {
    __syncthreads();  // previous tile's K/V reads done
    {
      int r = tid >> 2, c = (tid & 3) * 16;
      const bf16t* ksrc = &qkv[(rowbase + kt * 64 + r) * 3072 + koff + c];
      *(bf16x8*)&Ks[r][c] = *(const bf16x8*)&ksrc[0];
      *(bf16x8*)&Ks[r][c + 8] = *(const bf16x8*)&ksrc[8];
      const bf16t* vsrc = &qkv[(rowbase + kt * 64 + r) * 3072 + voff + c];
      bf16x8 v0 = *(const bf16x8*)&vsrc[0];
      bf16x8 v1 = *(const bf16x8*)&vsrc[8];
#pragma unroll
      for (int q2 = 0; q2 < 8; q2++) {
        Vt[c + q2][r] = v0[q2];
        Vt[c + 8 + q2][r] = v1[q2];
      }
    }
    __syncthreads();

    // S = Q K^T for this wave's 16 rows (4 col-tiles x K=64)
    f32x4 s[4];
#pragma unroll
    for (int jt = 0; jt < 4; jt++) {
      int jc = jt * 16 + lr;
      bf16x8 kb0 = ld8(&Ks[jc][4 * g], &Ks[jc][16 + 4 * g]);
      bf16x8 kb1 = ld8(&Ks[jc][32 + 4 * g], &Ks[jc][48 + 4 * g]);
      f32x4 t = f4zero();
      t = mfma16(qa0, kb0, t);
      t = mfma16(qa1, kb1, t);
      s[jt] = t;
    }

    // online softmax; lane holds rows 4g+r (r=reg), cols jt*16+lr
    float tm[4];
#pragma unroll
    for (int r = 0; r < 4; r++) tm[r] = -1e30f;
#pragma unroll
    for (int jt = 0; jt < 4; jt++)
#pragma unroll
      for (int r = 0; r < 4; r++) {
        float x = s[jt][r] * 0.125f;
        s[jt][r] = x;
        tm[r] = fmaxf(tm[r], x);
      }
#pragma unroll
    for (int m = 1; m < 16; m <<= 1)
#pragma unroll
      for (int r = 0; r < 4; r++) tm[r] = fmaxf(tm[r], __shfl_xor(tm[r], m, 64));

    float corr[4], tsum[4];
#pragma unroll
    for (int r = 0; r < 4; r++) {
      float mnew = fmaxf(mrun[r], tm[r]);
      corr[r] = __expf(mrun[r] - mnew);
      mrun[r] = mnew;
      tsum[r] = 0.f;
    }
#pragma unroll
    for (int jt = 0; jt < 4; jt++)
#pragma unroll
      for (int r = 0; r < 4; r++) {
        float pv = __expf(s[jt][r] - mrun[r]);
        s[jt][r] = pv;
        tsum[r] += pv;
      }
#pragma unroll
    for (int m = 1; m < 16; m <<= 1)
#pragma unroll
      for (int r = 0; r < 4; r++) tsum[r] += __shfl_xor(tsum[r], m, 64);
#pragma unroll
    for (int r = 0; r < 4; r++) lrun[r] = lrun[r] * corr[r] + tsum[r];
#pragma unroll
    for (int jt = 0; jt < 4; jt++)
#pragma unroll
      for (int r = 0; r < 4; r++) acc_o[jt][r] *= corr[r];

    // P -> LDS (bf16); rows are wave-private so no cross-wave barrier needed
#pragma unroll
    for (int jt = 0; jt < 4; jt++)
#pragma unroll
      for (int r = 0; r < 4; r++) Ps[w * 16 + 4 * g + r][jt * 16 + lr] = (bf16t)s[jt][r];

    const int pr = w * 16 + lr;
    bf16x8 pa0 = ld8(&Ps[pr][4 * g], &Ps[pr][16 + 4 * g]);
    bf16x8 pa1 = ld8(&Ps[pr][32 + 4 * g], &Ps[pr][48 + 4 * g]);
#pragma unroll
    for (int dt = 0; dt < 4; dt++) {
      int dc = dt * 16 + lr;
      bf16x8 vb0 = ld8(&Vt[dc][4 * g], &Vt[dc][16 + 4 * g]);
      bf16x8 vb1 = ld8(&Vt[dc][32 + 4 * g], &Vt[dc][48 + 4 * g]);
      acc_o[dt] = mfma16(pa0, vb0, acc_o[dt]);
      acc_o[dt] = mfma16(pa1, vb1, acc_o[dt]);
    }
  }

#pragma unroll
  for (int dt = 0; dt < 4; dt++) {
#pragma unroll
    for (int r = 0; r < 4; r++) {
      long row = qrow0 + w * 16 + 4 * g + r;
      o[row * (long)DM + h * 64 + dt * 16 + lr] = (bf16t)(acc_o[dt][r] / lrun[r]);
    }
  }
}

// ---------------- LayerNorm: x[row][1024] f32 -> bf16 out and/or f32 out ----------------
__global__ __launch_bounds__(256) void ln_kernel(const float* __restrict__ x,
                                                 const float* __restrict__ gamma,
                                                 const float* __restrict__ beta,
                                                 bf16t* __restrict__ out_bf,
                                                 float* __restrict__ out_f32) {
  const long row = blockIdx.x;
  const int tid = threadIdx.x;
  const float* xr = x + row * DM;
  f32x4 v = *(const f32x4*)&xr[tid * 4];
  float s = v[0] + v[1] + v[2] + v[3];
  float ss = v[0] * v[0] + v[1] * v[1] + v[2] * v[2] + v[3] * v[3];
#pragma unroll
  for (int m = 1; m < 64; m <<= 1) {
    s += __shfl_xor(s, m, 64);
    ss += __shfl_xor(ss, m, 64);
  }
  __shared__ float red[8];
  const int w = tid >> 6, lane = tid & 63;
  if (lane == 0) {
    red[w] = s;
    red[4 + w] = ss;
  }
  __syncthreads();
  s = red[0] + red[1] + red[2] + red[3];
  ss = red[4] + red[5] + red[6] + red[7];
  float mean = s * (1.f / DM);
  float var = ss * (1.f / DM) - mean * mean;
  float inv = rsqrtf(var + 1e-5f);
  f32x4 ga = *(const f32x4*)&gamma[tid * 4];
  f32x4 be = *(const f32x4*)&beta[tid * 4];
  bf16x4 ob;
  f32x4 of;
#pragma unroll
  for (int c = 0; c < 4; c++) {
    float y = (v[c] - mean) * inv * ga[c] + be[c];
    ob[c] = (bf16t)y;
    of[c] = y;
  }
  long base = row * DM + tid * 4;
  if (out_bf) *(bf16x4*)&out_bf[base] = ob;
  if (out_f32) *(f32x4*)&out_f32[base] = of;
}

extern "C" void kernel_launch(void* const* d_in, const int* in_sizes, int n_in,
                              void* d_out, int out_size, void* d_ws, size_t ws_size,
                              hipStream_t stream) {
  const float* z = (const float*)d_in[0];
  const float* Wq = (const float*)d_in[1];
  const float* bq = (const float*)d_in[2];
  const float* Wk = (const float*)d_in[3];
  const float* bk = (const float*)d_in[4];
  const float* Wv = (const float*)d_in[5];
  const float* bv = (const float*)d_in[6];
  const float* Wo = (const float*)d_in[7];
  const float* bo = (const float*)d_in[8];
  const float* W1 = (const float*)d_in[9];
  const float* b1 = (const float*)d_in[10];
  const float* W2 = (const float*)d_in[11];
  const float* b2 = (const float*)d_in[12];
  const float* g1 = (const float*)d_in[13];
  const float* be1 = (const float*)d_in[14];
  const float* g2 = (const float*)d_in[15];
  const float* be2 = (const float*)d_in[16];

  char* p = (char*)d_ws;
  auto alloc = [&](size_t bytes) {
    char* r = p;
    p += (bytes + 255) & ~(size_t)255;
    return r;
  };
  bf16t* wqkvT = (bf16t*)alloc((size_t)3072 * 1024 * 2);  // [3072][1024]
  float* bqkv = (float*)alloc((size_t)3072 * 4);
  bf16t* woT = (bf16t*)alloc((size_t)1024 * 1024 * 2);    // [1024][1024]
  bf16t* w1T = (bf16t*)alloc((size_t)4096 * 1024 * 2);    // [4096][1024]
  bf16t* w2T = (bf16t*)alloc((size_t)1024 * 4096 * 2);    // [1024][4096]
  bf16t* act = (bf16t*)alloc((size_t)BT * 1024 * 2);
  bf16t* obuf = (bf16t*)alloc((size_t)BT * 1024 * 2);
  bf16t* big = (bf16t*)alloc((size_t)BT * 4096 * 2);  // qkv[M][3072] and ffn-h[M][4096] share
  float* tbuf = (float*)alloc((size_t)BT * 1024 * 4);
  float* residf = (float*)alloc((size_t)BT * 1024 * 4);

  pack_qkv_t_kernel<<<dim3(48, 16), dim3(256), 0, stream>>>(Wq, Wk, Wv, wqkvT);
  pack_bias_kernel<<<dim3(12), dim3(256), 0, stream>>>(bq, bk, bv, bqkv);
  tcvt_kernel<<<dim3(16, 16), dim3(256), 0, stream>>>(Wo, woT, 1024, 1024);
  tcvt_kernel<<<dim3(64, 16), dim3(256), 0, stream>>>(W1, w1T, 1024, 4096);
  tcvt_kernel<<<dim3(16, 64), dim3(256), 0, stream>>>(W2, w2T, 4096, 1024);
  cvt_kernel<<<dim3(8192), dim3(256), 0, stream>>>(z, act, (long)BT * 1024);

  for (int iter = 0; iter < 2; ++iter) {
    // QKV projection
    gemm_kernel<0><<<dim3(24, 64), dim3(256), 0, stream>>>(
        act, wqkvT, bqkv, (const float*)nullptr, (void*)big, BT, 3072, 1024);
    // attention
    attn_kernel<<<dim3(128, 16), dim3(256), 0, stream>>>(big, obuf);
    // O-projection + residual
    const float* rsrc = (iter == 0) ? z : residf;
    gemm_kernel<2><<<dim3(8, 64), dim3(256), 0, stream>>>(
        obuf, woT, bo, rsrc, (void*)tbuf, BT, 1024, 1024);
    if (iter == 1) {
      // final LN1 -> d_out (f32); z_refined is LN1 output of last iteration
      ln_kernel<<<dim3(8192), dim3(256), 0, stream>>>(tbuf, g1, be1, (bf16t*)nullptr,
                                                      (float*)d_out);
      break;
    }
    ln_kernel<<<dim3(8192), dim3(256), 0, stream>>>(tbuf, g1, be1, act, residf);
    // FFN
    gemm_kernel<1><<<dim3(32, 64), dim3(256), 0, stream>>>(
        act, w1T, b1, (const float*)nullptr, (void*)big, BT, 4096, 1024);
    gemm_kernel<2><<<dim3(8, 64), dim3(256), 0, stream>>>(
        big, w2T, b2, residf, (void*)tbuf, BT, 1024, 4096);
    ln_kernel<<<dim3(8192), dim3(256), 0, stream>>>(tbuf, g2, be2, act, residf);
  }
}

// Round 4
// 702.327 us; speedup vs baseline: 2.4184x; 1.1793x over previous
//
#include <hip/hip_runtime.h>
#include <hip/hip_bf16.h>

typedef __bf16 bf16t;
typedef bf16t bf16x4 __attribute__((ext_vector_type(4)));
typedef bf16t bf16x8 __attribute__((ext_vector_type(8)));
typedef float f32x4 __attribute__((ext_vector_type(4)));

#define BT 8192      // B*T rows
#define TT 1024      // T
#define DM 1024      // d_model
#define DFF 4096

static __device__ __forceinline__ f32x4 mfma16(bf16x8 a, bf16x8 b, f32x4 c) {
  return __builtin_amdgcn_mfma_f32_16x16x32_bf16(a, b, c, 0, 0, 0);
}
static __device__ __forceinline__ bf16x8 ld8(const bf16t* p0, const bf16t* p1) {
  bf16x4 lo = *(const bf16x4*)p0;
  bf16x4 hi = *(const bf16x4*)p1;
  return __builtin_shufflevector(lo, hi, 0, 1, 2, 3, 4, 5, 6, 7);
}
static __device__ __forceinline__ f32x4 f4zero() {
  f32x4 z = {0.f, 0.f, 0.f, 0.f};
  return z;
}
static __device__ __forceinline__ f32x4 vmax4(f32x4 a, f32x4 b) {
  f32x4 r;
#pragma unroll
  for (int i = 0; i < 4; i++) r[i] = fmaxf(a[i], b[i]);
  return r;
}
// async global->LDS, 16 bytes per lane; lds dest = wave-uniform base + lane*16
static __device__ __forceinline__ void gld16(const bf16t* g, bf16t* l) {
  __builtin_amdgcn_global_load_lds((const __attribute__((address_space(1))) void*)g,
                                   (__attribute__((address_space(3))) void*)l, 16, 0, 0);
}

// ---------------- f32 -> bf16 convert (no transpose) ----------------
__global__ __launch_bounds__(256) void cvt_kernel(const float* __restrict__ in,
                                                  bf16t* __restrict__ out, long n) {
  long i = ((long)blockIdx.x * 256 + threadIdx.x) * 4;
  if (i >= n) return;
  f32x4 v = *(const f32x4*)&in[i];
  bf16x4 o = {(bf16t)v[0], (bf16t)v[1], (bf16t)v[2], (bf16t)v[3]};
  *(bf16x4*)&out[i] = o;
}

// ---------------- transpose-convert: out[N][M] = (bf16) in[M][N], 64x64 LDS tiles ----------------
__global__ __launch_bounds__(256) void tcvt_kernel(const float* __restrict__ in,
                                                   bf16t* __restrict__ out, int M, int N) {
  __shared__ float T[64][65];
  const int t = threadIdx.x;
  const int ty = t >> 6, tx = t & 63;
  const long n0 = (long)blockIdx.x * 64, m0 = (long)blockIdx.y * 64;
#pragma unroll
  for (int p = 0; p < 16; ++p) {
    int a = ty * 16 + p;
    T[a][tx] = in[(m0 + a) * N + n0 + tx];
  }
  __syncthreads();
#pragma unroll
  for (int p = 0; p < 16; ++p) {
    int r = ty * 16 + p;
    out[(n0 + r) * M + m0 + tx] = (bf16t)T[tx][r];
  }
}

// ---------------- V-transpose: qkv[M][3072] cols 2048.. -> vT[bh][64 d][1024 t] ----------------
__global__ __launch_bounds__(256) void vtrans_kernel(const bf16t* __restrict__ qkv,
                                                     bf16t* __restrict__ vT) {
  __shared__ bf16t T[64][72];
  const int bh = blockIdx.x;  // 0..127
  const int b = bh >> 4, h = bh & 15;
  const int tt = blockIdx.y;  // 0..15
  const int t = threadIdx.x;
  const int ty = t >> 6, tx = t & 63;
  const long srcbase = ((long)b * TT + tt * 64) * 3072 + 2048 + h * 64;
#pragma unroll
  for (int p = 0; p < 16; ++p) {
    int a = ty * 16 + p;
    T[a][tx] = qkv[srcbase + (long)a * 3072 + tx];
  }
  __syncthreads();
  const long dstbase = ((long)bh * 64) * 1024 + tt * 64;
#pragma unroll
  for (int p = 0; p < 16; ++p) {
    int d = ty * 16 + p;
    vT[dstbase + (long)d * 1024 + tx] = T[tx][d];
  }
}

// ---------------- pack Wq/Wk/Wv [H][D][Dh] -> transposed [3072][1024] bf16 ----------------
__global__ __launch_bounds__(256) void pack_qkv_t_kernel(const float* __restrict__ Wq,
                                                         const float* __restrict__ Wk,
                                                         const float* __restrict__ Wv,
                                                         bf16t* __restrict__ WT) {
  __shared__ float T[64][65];
  const int bx = blockIdx.x;  // 0..47 : sel*16 + h
  const int sel = bx >> 4, h = bx & 15;
  const float* src = ((sel == 0) ? Wq : (sel == 1) ? Wk : Wv) + (long)h * 65536;  // [1024][64]
  const long nbase = (long)sel * 1024 + h * 64;
  const long m0 = (long)blockIdx.y * 64;  // d tile
  const int t = threadIdx.x;
  const int ty = t >> 6, tx = t & 63;
#pragma unroll
  for (int p = 0; p < 16; ++p) {
    int a = ty * 16 + p;
    T[a][tx] = src[(m0 + a) * 64 + tx];  // [d_local][kk]
  }
  __syncthreads();
#pragma unroll
  for (int p = 0; p < 16; ++p) {
    int r = ty * 16 + p;  // kk
    WT[(nbase + r) * 1024 + m0 + tx] = (bf16t)T[tx][r];
  }
}

__global__ __launch_bounds__(256) void pack_bias_kernel(const float* __restrict__ bq,
                                                        const float* __restrict__ bk,
                                                        const float* __restrict__ bv,
                                                        float* __restrict__ bqkv) {
  int i = blockIdx.x * 256 + threadIdx.x;
  if (i >= 3072) return;
  int sel = i >> 10, c = i & 1023;
  bqkv[i] = ((sel == 0) ? bq : (sel == 1) ? bk : bv)[c];
}

// ---------------- GEMM: C[M,N] = A[M,K](bf16) * B^T  where Bt is [N][K](bf16) ----------------
// 128x128 tile, BK=32, global_load_lds staging, XOR-swizzled LDS (T2, both-sides),
// 2-phase double-buffer (T3-minimal), 1 barrier per K-step.
template <int EPI>
__global__ __launch_bounds__(256) void gemm_kernel(
    const bf16t* __restrict__ A, const bf16t* __restrict__ Bt,
    const float* __restrict__ bias, const float* __restrict__ resid,
    void* __restrict__ Cout, int M, int N, int K) {
  __shared__ bf16t As[2 * 128 * 32];
  __shared__ bf16t Bs[2 * 128 * 32];
  const int tid = threadIdx.x;
  const int lane = tid & 63;
  const int wid = tid >> 6;
  const int wr = wid >> 1, wc = wid & 1;
  const int g = lane >> 4, lr = lane & 15;
  const long brow = (long)blockIdx.y * 128;
  const long bcol = (long)blockIdx.x * 128;

  f32x4 acc[4][4];
#pragma unroll
  for (int i = 0; i < 4; i++)
#pragma unroll
    for (int j = 0; j < 4; j++) acc[i][j] = f4zero();

  const int srow = tid >> 2;                       // 0..63 row within round
  const int csrc = (tid & 3) ^ ((tid >> 3) & 3);   // pre-swizzled global 16B-chunk
  const bf16t* gA = &A[(brow + srow) * (long)K + 8 * csrc];
  const bf16t* gB = &Bt[(bcol + srow) * (long)K + 8 * csrc];
  bf16t* lA = As + wid * 512;  // wave-uniform base
  bf16t* lB = Bs + wid * 512;

  const int xsw = ((lr >> 1) & 3) << 3;
  const int ra0 = (4 * g) ^ xsw;
  const int ra1 = (16 + 4 * g) ^ xsw;

  auto stage = [&](int buf, int k0) {
    gld16(gA + k0, lA + buf * 4096);
    gld16(gA + k0 + (long)64 * K, lA + buf * 4096 + 2048);
    gld16(gB + k0, lB + buf * 4096);
    gld16(gB + k0 + (long)64 * K, lB + buf * 4096 + 2048);
  };

  stage(0, 0);
  __syncthreads();

  int cur = 0;
  for (int k0 = 32; k0 < K; k0 += 32) {
    stage(cur ^ 1, k0);
    bf16x8 af[4], bfv[4];
#pragma unroll
    for (int i = 0; i < 4; i++) {
      const bf16t* r = As + cur * 4096 + (wr * 64 + i * 16 + lr) * 32;
      af[i] = ld8(r + ra0, r + ra1);
    }
#pragma unroll
    for (int j = 0; j < 4; j++) {
      const bf16t* c = Bs + cur * 4096 + (wc * 64 + j * 16 + lr) * 32;
      bfv[j] = ld8(c + ra0, c + ra1);
    }
#pragma unroll
    for (int i = 0; i < 4; i++)
#pragma unroll
      for (int j = 0; j < 4; j++) acc[i][j] = mfma16(af[i], bfv[j], acc[i][j]);
    __syncthreads();
    cur ^= 1;
  }
  {
    bf16x8 af[4], bfv[4];
#pragma unroll
    for (int i = 0; i < 4; i++) {
      const bf16t* r = As + cur * 4096 + (wr * 64 + i * 16 + lr) * 32;
      af[i] = ld8(r + ra0, r + ra1);
    }
#pragma unroll
    for (int j = 0; j < 4; j++) {
      const bf16t* c = Bs + cur * 4096 + (wc * 64 + j * 16 + lr) * 32;
      bfv[j] = ld8(c + ra0, c + ra1);
    }
#pragma unroll
    for (int i = 0; i < 4; i++)
#pragma unroll
      for (int j = 0; j < 4; j++) acc[i][j] = mfma16(af[i], bfv[j], acc[i][j]);
  }

#pragma unroll
  for (int j = 0; j < 4; j++) {
    int col = (int)bcol + wc * 64 + j * 16 + lr;
    float bval = bias ? bias[col] : 0.f;
#pragma unroll
    for (int i = 0; i < 4; i++) {
      long row0 = brow + wr * 64 + i * 16 + 4 * g;
#pragma unroll
      for (int r2 = 0; r2 < 4; r2++) {
        long row = row0 + r2;
        float v = acc[i][j][r2] + bval;
        if (EPI == 0) {
          ((bf16t*)Cout)[row * N + col] = (bf16t)v;
        } else if (EPI == 1) {
          ((bf16t*)Cout)[row * N + col] = (bf16t)fmaxf(v, 0.f);
        } else {
          ((float*)Cout)[row * N + col] = v + resid[row * N + col];
        }
      }
    }
  }
}

// ---------------- flash attention, swapped-QK^T in-register softmax ----------------
// qkv[M][3072] bf16 (Q,K parts), vT[bh][64][1024] bf16 -> o[M][1024] bf16.
// All LDS tiles are [64 rows][64 elems]; phys elem = logical ^ ((row&7)<<3).
// Staged via global_load_lds with pre-swizzled global source chunks.
__global__ __launch_bounds__(256) void attn_kernel(const bf16t* __restrict__ qkv,
                                                   const bf16t* __restrict__ vT,
                                                   bf16t* __restrict__ o) {
  const int bh = blockIdx.x;  // 0..127
  const int b = bh >> 4, h = bh & 15;
  const int qt = blockIdx.y;  // 0..15
  const int tid = threadIdx.x;
  const int lane = tid & 63;
  const int w = tid >> 6;
  const int g = lane >> 4, lr = lane & 15;

  __shared__ bf16t Qs[64 * 64];
  __shared__ bf16t Ks[2][64 * 64];
  __shared__ bf16t Vs[2][64 * 64];

  const long rowbase = (long)b * TT;
  const long qrow0 = rowbase + (long)qt * 64;

  // staging geometry: per call, wave w lane l fills LDS rows (c*32 + w*8 + (l>>3)),
  // 16B chunk (l&7); source chunk pre-swizzled by ^((l>>3)&7).
  const int srow_in_call = w * 8 + (lane >> 3);          // 0..31
  const int schunk = (lane & 7) ^ ((lane >> 3) & 7);     // swizzled source chunk
  const int soff = 8 * schunk;                           // elem offset in 64-elem row

  const bf16t* qsrc = &qkv[(qrow0 + srow_in_call) * 3072 + h * 64 + soff];
  const bf16t* ksrc = &qkv[(rowbase + srow_in_call) * 3072 + 1024 + h * 64 + soff];
  const bf16t* vsrc = &vT[((long)bh * 64 + srow_in_call) * 1024 + soff];
  bf16t* ldst = (bf16t*)((w * 8) * 64);  // numeric wave base offset (elems)

  auto stageQ = [&]() {
    gld16(qsrc, Qs + (size_t)ldst);
    gld16(qsrc + (long)32 * 3072, Qs + (size_t)ldst + 32 * 64);
  };
  auto stageK = [&](int buf, int kt) {
    const bf16t* s = ksrc + (long)kt * 64 * 3072;
    gld16(s, Ks[buf] + (size_t)ldst);
    gld16(s + (long)32 * 3072, Ks[buf] + (size_t)ldst + 32 * 64);
  };
  auto stageV = [&](int buf, int kt) {
    const bf16t* s = vsrc + kt * 64;
    gld16(s, Vs[buf] + (size_t)ldst);
    gld16(s + (long)32 * 1024, Vs[buf] + (size_t)ldst + 32 * 64);
  };

  stageQ();
  stageK(0, 0);
  stageV(0, 0);
  __syncthreads();  // vmcnt(0) drained: tile 0 + Q ready

  // read-side swizzle offsets (rows used below are all ≡ lr mod 8 in &7)
  const int swk = (lr & 7) << 3;
  const int o0 = (4 * g) ^ swk, o1 = (16 + 4 * g) ^ swk;
  const int o2 = (32 + 4 * g) ^ swk, o3 = (48 + 4 * g) ^ swk;

  // Q fragments (B-operand: col=q=lr, contraction d): wave w's q-rows = w*16+lr
  const bf16t* qrow = Qs + (w * 16 + lr) * 64;
  const bf16x8 qb_lo = ld8(qrow + o0, qrow + o1);  // d 0..31
  const bf16x8 qb_hi = ld8(qrow + o2, qrow + o3);  // d 32..63

  f32x4 acc_o[4];
#pragma unroll
  for (int j = 0; j < 4; j++) acc_o[j] = f4zero();
  float mrun = -1e30f, lrun = 0.f;  // stats for q = w*16 + lr (lr-domain)

  int cur = 0;
  for (int kt = 0; kt < 16; ++kt) {
    if (kt < 15) {
      stageK(cur ^ 1, kt + 1);
      stageV(cur ^ 1, kt + 1);
    }

    // S^T = K * Q^T : s[jt] holds S[k=jt*16+4g+r][q=lr]
    f32x4 s[4];
#pragma unroll
    for (int jt = 0; jt < 4; jt++) {
      const bf16t* krow = Ks[cur] + (jt * 16 + lr) * 64;
      bf16x8 ka_lo = ld8(krow + o0, krow + o1);
      bf16x8 ka_hi = ld8(krow + o2, krow + o3);
      f32x4 t = f4zero();
      t = mfma16(ka_lo, qb_lo, t);
      t = mfma16(ka_hi, qb_hi, t);
      s[jt] = t;
    }

    // scale + in-lane row stats (all 16 values belong to q=lr)
#pragma unroll
    for (int jt = 0; jt < 4; jt++)
#pragma unroll
      for (int r = 0; r < 4; r++) s[jt][r] *= 0.125f;

    f32x4 mv = vmax4(vmax4(s[0], s[1]), vmax4(s[2], s[3]));
    float tm = fmaxf(fmaxf(mv[0], mv[1]), fmaxf(mv[2], mv[3]));
    tm = fmaxf(tm, __shfl_xor(tm, 16, 64));
    tm = fmaxf(tm, __shfl_xor(tm, 32, 64));

    float mnew = fmaxf(mrun, tm);
    float corr = __expf(mrun - mnew);
    mrun = mnew;

    f32x4 sv = f4zero();
#pragma unroll
    for (int jt = 0; jt < 4; jt++)
#pragma unroll
      for (int r = 0; r < 4; r++) {
        float pv = __expf(s[jt][r] - mnew);
        s[jt][r] = pv;
        sv[r] += pv;
      }
    float tsum = sv[0] + sv[1] + sv[2] + sv[3];
    tsum += __shfl_xor(tsum, 16, 64);
    tsum += __shfl_xor(tsum, 32, 64);
    lrun = lrun * corr + tsum;

    // fetch corr for q = 4g+r (held by lane 20g+r) and rescale O accumulator
#pragma unroll
    for (int r = 0; r < 4; r++) {
      float cq = __shfl(corr, 20 * g + r, 64);
#pragma unroll
      for (int dt = 0; dt < 4; dt++) acc_o[dt][r] *= cq;
    }

    // P already in A-fragment layout: row=q=lr, k=4g+e (+16 half)
    bf16x8 pa0, pa1;
#pragma unroll
    for (int r = 0; r < 4; r++) {
      pa0[r] = (bf16t)s[0][r];
      pa0[r + 4] = (bf16t)s[1][r];
      pa1[r] = (bf16t)s[2][r];
      pa1[r + 4] = (bf16t)s[3][r];
    }

#pragma unroll
    for (int dt = 0; dt < 4; dt++) {
      const bf16t* vrow = Vs[cur] + (dt * 16 + lr) * 64;
      bf16x8 vb_lo = ld8(vrow + o0, vrow + o1);
      bf16x8 vb_hi = ld8(vrow + o2, vrow + o3);
      acc_o[dt] = mfma16(pa0, vb_lo, acc_o[dt]);
      acc_o[dt] = mfma16(pa1, vb_hi, acc_o[dt]);
    }

    __syncthreads();  // next tile staged (vmcnt drained) + guards buffer reuse
    cur ^= 1;
  }

  // epilogue: O[q = w*16 + 4g + r][d = dt*16 + lr]
  float inv = 1.0f / lrun;
#pragma unroll
  for (int r = 0; r < 4; r++) {
    float iq = __shfl(inv, 20 * g + r, 64);
    long row = qrow0 + w * 16 + 4 * g + r;
#pragma unroll
    for (int dt = 0; dt < 4; dt++) {
      o[row * (long)DM + h * 64 + dt * 16 + lr] = (bf16t)(acc_o[dt][r] * iq);
    }
  }
}

// ---------------- LayerNorm: x[row][1024] f32 -> bf16 out and/or f32 out ----------------
__global__ __launch_bounds__(256) void ln_kernel(const float* __restrict__ x,
                                                 const float* __restrict__ gamma,
                                                 const float* __restrict__ beta,
                                                 bf16t* __restrict__ out_bf,
                                                 float* __restrict__ out_f32) {
  const long row = blockIdx.x;
  const int tid = threadIdx.x;
  const float* xr = x + row * DM;
  f32x4 v = *(const f32x4*)&xr[tid * 4];
  float s = v[0] + v[1] + v[2] + v[3];
  float ss = v[0] * v[0] + v[1] * v[1] + v[2] * v[2] + v[3] * v[3];
#pragma unroll
  for (int m = 1; m < 64; m <<= 1) {
    s += __shfl_xor(s, m, 64);
    ss += __shfl_xor(ss, m, 64);
  }
  __shared__ float red[8];
  const int w = tid >> 6, lane = tid & 63;
  if (lane == 0) {
    red[w] = s;
    red[4 + w] = ss;
  }
  __syncthreads();
  s = red[0] + red[1] + red[2] + red[3];
  ss = red[4] + red[5] + red[6] + red[7];
  float mean = s * (1.f / DM);
  float var = ss * (1.f / DM) - mean * mean;
  float inv = rsqrtf(var + 1e-5f);
  f32x4 ga = *(const f32x4*)&gamma[tid * 4];
  f32x4 be = *(const f32x4*)&beta[tid * 4];
  bf16x4 ob;
  f32x4 of;
#pragma unroll
  for (int c = 0; c < 4; c++) {
    float y = (v[c] - mean) * inv * ga[c] + be[c];
    ob[c] = (bf16t)y;
    of[c] = y;
  }
  long base = row * DM + tid * 4;
  if (out_bf) *(bf16x4*)&out_bf[base] = ob;
  if (out_f32) *(f32x4*)&out_f32[base] = of;
}

extern "C" void kernel_launch(void* const* d_in, const int* in_sizes, int n_in,
                              void* d_out, int out_size, void* d_ws, size_t ws_size,
                              hipStream_t stream) {
  const float* z = (const float*)d_in[0];
  const float* Wq = (const float*)d_in[1];
  const float* bq = (const float*)d_in[2];
  const float* Wk = (const float*)d_in[3];
  const float* bk = (const float*)d_in[4];
  const float* Wv = (const float*)d_in[5];
  const float* bv = (const float*)d_in[6];
  const float* Wo = (const float*)d_in[7];
  const float* bo = (const float*)d_in[8];
  const float* W1 = (const float*)d_in[9];
  const float* b1 = (const float*)d_in[10];
  const float* W2 = (const float*)d_in[11];
  const float* b2 = (const float*)d_in[12];
  const float* g1 = (const float*)d_in[13];
  const float* be1 = (const float*)d_in[14];
  const float* g2 = (const float*)d_in[15];
  const float* be2 = (const float*)d_in[16];

  char* p = (char*)d_ws;
  auto alloc = [&](size_t bytes) {
    char* r = p;
    p += (bytes + 255) & ~(size_t)255;
    return r;
  };
  bf16t* wqkvT = (bf16t*)alloc((size_t)3072 * 1024 * 2);  // [3072][1024]
  float* bqkv = (float*)alloc((size_t)3072 * 4);
  bf16t* woT = (bf16t*)alloc((size_t)1024 * 1024 * 2);    // [1024][1024]
  bf16t* w1T = (bf16t*)alloc((size_t)4096 * 1024 * 2);    // [4096][1024]
  bf16t* w2T = (bf16t*)alloc((size_t)1024 * 4096 * 2);    // [1024][4096]
  bf16t* act = (bf16t*)alloc((size_t)BT * 1024 * 2);
  bf16t* obuf = (bf16t*)alloc((size_t)BT * 1024 * 2);
  bf16t* big = (bf16t*)alloc((size_t)BT * 4096 * 2);  // qkv[M][3072] / ffn-h[M][4096]
  float* tbuf = (float*)alloc((size_t)BT * 1024 * 4);
  float* residf = (float*)alloc((size_t)BT * 1024 * 4);
  // vT aliases tbuf: tbuf is only live from WO-gemm output to LN input;
  // vT is only live from vtrans to end of attn. Disjoint lifetimes.
  bf16t* vT = (bf16t*)tbuf;  // [128][64][1024] = 16 MB

  pack_qkv_t_kernel<<<dim3(48, 16), dim3(256), 0, stream>>>(Wq, Wk, Wv, wqkvT);
  pack_bias_kernel<<<dim3(12), dim3(256), 0, stream>>>(bq, bk, bv, bqkv);
  tcvt_kernel<<<dim3(16, 16), dim3(256), 0, stream>>>(Wo, woT, 1024, 1024);
  tcvt_kernel<<<dim3(64, 16), dim3(256), 0, stream>>>(W1, w1T, 1024, 4096);
  tcvt_kernel<<<dim3(16, 64), dim3(256), 0, stream>>>(W2, w2T, 4096, 1024);
  cvt_kernel<<<dim3(8192), dim3(256), 0, stream>>>(z, act, (long)BT * 1024);

  for (int iter = 0; iter < 2; ++iter) {
    // QKV projection
    gemm_kernel<0><<<dim3(24, 64), dim3(256), 0, stream>>>(
        act, wqkvT, bqkv, (const float*)nullptr, (void*)big, BT, 3072, 1024);
    // V transpose to [bh][d][t]
    vtrans_kernel<<<dim3(128, 16), dim3(256), 0, stream>>>(big, vT);
    // attention
    attn_kernel<<<dim3(128, 16), dim3(256), 0, stream>>>(big, vT, obuf);
    // O-projection + residual
    const float* rsrc = (iter == 0) ? z : residf;
    gemm_kernel<2><<<dim3(8, 64), dim3(256), 0, stream>>>(
        obuf, woT, bo, rsrc, (void*)tbuf, BT, 1024, 1024);
    if (iter == 1) {
      ln_kernel<<<dim3(8192), dim3(256), 0, stream>>>(tbuf, g1, be1, (bf16t*)nullptr,
                                                      (float*)d_out);
      break;
    }
    ln_kernel<<<dim3(8192), dim3(256), 0, stream>>>(tbuf, g1, be1, act, residf);
    // FFN
    gemm_kernel<1><<<dim3(32, 64), dim3(256), 0, stream>>>(
        act, w1T, b1, (const float*)nullptr, (void*)big, BT, 4096, 1024);
    gemm_kernel<2><<<dim3(8, 64), dim3(256), 0, stream>>>(
        big, w2T, b2, residf, (void*)tbuf, BT, 1024, 4096);
    ln_kernel<<<dim3(8192), dim3(256), 0, stream>>>(tbuf, g2, be2, act, residf);
  }
}

// Round 5
// 696.001 us; speedup vs baseline: 2.4404x; 1.0091x over previous
//
#include <hip/hip_runtime.h>
#include <hip/hip_bf16.h>

typedef __bf16 bf16t;
typedef bf16t bf16x4 __attribute__((ext_vector_type(4)));
typedef bf16t bf16x8 __attribute__((ext_vector_type(8)));
typedef float f32x4 __attribute__((ext_vector_type(4)));

#define BT 8192      // B*T rows
#define TT 1024      // T
#define DM 1024      // d_model
#define DFF 4096

static __device__ __forceinline__ f32x4 mfma16(bf16x8 a, bf16x8 b, f32x4 c) {
  return __builtin_amdgcn_mfma_f32_16x16x32_bf16(a, b, c, 0, 0, 0);
}
static __device__ __forceinline__ bf16x8 ld8(const bf16t* p0, const bf16t* p1) {
  bf16x4 lo = *(const bf16x4*)p0;
  bf16x4 hi = *(const bf16x4*)p1;
  return __builtin_shufflevector(lo, hi, 0, 1, 2, 3, 4, 5, 6, 7);
}
static __device__ __forceinline__ f32x4 f4zero() {
  f32x4 z = {0.f, 0.f, 0.f, 0.f};
  return z;
}
static __device__ __forceinline__ f32x4 vmax4(f32x4 a, f32x4 b) {
  f32x4 r;
#pragma unroll
  for (int i = 0; i < 4; i++) r[i] = fmaxf(a[i], b[i]);
  return r;
}
// async global->LDS, 16 bytes per lane; lds dest = wave-uniform base + lane*16
static __device__ __forceinline__ void gld16(const bf16t* g, bf16t* l) {
  __builtin_amdgcn_global_load_lds((const __attribute__((address_space(1))) void*)g,
                                   (__attribute__((address_space(3))) void*)l, 16, 0, 0);
}

// ---------------- f32 -> bf16 convert (no transpose) ----------------
__global__ __launch_bounds__(256) void cvt_kernel(const float* __restrict__ in,
                                                  bf16t* __restrict__ out, long n) {
  long i = ((long)blockIdx.x * 256 + threadIdx.x) * 4;
  if (i >= n) return;
  f32x4 v = *(const f32x4*)&in[i];
  bf16x4 o = {(bf16t)v[0], (bf16t)v[1], (bf16t)v[2], (bf16t)v[3]};
  *(bf16x4*)&out[i] = o;
}

// ---------------- transpose-convert: out[N][M] = (bf16) in[M][N], 64x64 LDS tiles ----------------
__global__ __launch_bounds__(256) void tcvt_kernel(const float* __restrict__ in,
                                                   bf16t* __restrict__ out, int M, int N) {
  __shared__ float T[64][65];
  const int t = threadIdx.x;
  const int ty = t >> 6, tx = t & 63;
  const long n0 = (long)blockIdx.x * 64, m0 = (long)blockIdx.y * 64;
#pragma unroll
  for (int p = 0; p < 16; ++p) {
    int a = ty * 16 + p;
    T[a][tx] = in[(m0 + a) * N + n0 + tx];
  }
  __syncthreads();
#pragma unroll
  for (int p = 0; p < 16; ++p) {
    int r = ty * 16 + p;
    out[(n0 + r) * M + m0 + tx] = (bf16t)T[tx][r];
  }
}

// ---------------- V-transpose: qkv[M][3072] cols 2048.. -> vT[bh][64 d][1024 t] ----------------
__global__ __launch_bounds__(256) void vtrans_kernel(const bf16t* __restrict__ qkv,
                                                     bf16t* __restrict__ vT) {
  __shared__ bf16t T[64][72];
  const int bh = blockIdx.x;  // 0..127
  const int b = bh >> 4, h = bh & 15;
  const int tt = blockIdx.y;  // 0..15
  const int t = threadIdx.x;
  const int ty = t >> 6, tx = t & 63;
  const long srcbase = ((long)b * TT + tt * 64) * 3072 + 2048 + h * 64;
#pragma unroll
  for (int p = 0; p < 16; ++p) {
    int a = ty * 16 + p;
    T[a][tx] = qkv[srcbase + (long)a * 3072 + tx];
  }
  __syncthreads();
  const long dstbase = ((long)bh * 64) * 1024 + tt * 64;
#pragma unroll
  for (int p = 0; p < 16; ++p) {
    int d = ty * 16 + p;
    vT[dstbase + (long)d * 1024 + tx] = T[tx][d];
  }
}

// ---------------- pack Wq/Wk/Wv [H][D][Dh] -> transposed [3072][1024] bf16 ----------------
__global__ __launch_bounds__(256) void pack_qkv_t_kernel(const float* __restrict__ Wq,
                                                         const float* __restrict__ Wk,
                                                         const float* __restrict__ Wv,
                                                         bf16t* __restrict__ WT) {
  __shared__ float T[64][65];
  const int bx = blockIdx.x;  // 0..47 : sel*16 + h
  const int sel = bx >> 4, h = bx & 15;
  const float* src = ((sel == 0) ? Wq : (sel == 1) ? Wk : Wv) + (long)h * 65536;  // [1024][64]
  const long nbase = (long)sel * 1024 + h * 64;
  const long m0 = (long)blockIdx.y * 64;  // d tile
  const int t = threadIdx.x;
  const int ty = t >> 6, tx = t & 63;
#pragma unroll
  for (int p = 0; p < 16; ++p) {
    int a = ty * 16 + p;
    T[a][tx] = src[(m0 + a) * 64 + tx];  // [d_local][kk]
  }
  __syncthreads();
#pragma unroll
  for (int p = 0; p < 16; ++p) {
    int r = ty * 16 + p;  // kk
    WT[(nbase + r) * 1024 + m0 + tx] = (bf16t)T[tx][r];
  }
}

__global__ __launch_bounds__(256) void pack_bias_kernel(const float* __restrict__ bq,
                                                        const float* __restrict__ bk,
                                                        const float* __restrict__ bv,
                                                        float* __restrict__ bqkv) {
  int i = blockIdx.x * 256 + threadIdx.x;
  if (i >= 3072) return;
  int sel = i >> 10, c = i & 1023;
  bqkv[i] = ((sel == 0) ? bq : (sel == 1) ? bk : bv)[c];
}

// ---------------- GEMM: C[M,N] = A[M,K](bf16) * B^T  where Bt is [N][K](bf16) ----------------
// 128x128 tile, BK=32, global_load_lds staging, XOR-swizzled LDS (T2, both-sides),
// 2-phase double-buffer, 1 barrier per K-step.
// 1-D grid with XCD-chunked swizzle (T1) + column-group-of-8 super-tile order for L2:
//   lid = (wg%8)*(nwg/8) + wg/8  (contiguous logical chunk per XCD; nwg%8==0)
//   group = lid/(8*gy); r = rem/8; c = group*8 + rem%8
// Per-XCD working set: 8 B-panels (2 MB) resident + A-tiles streaming.
template <int EPI>
__global__ __launch_bounds__(256) void gemm_kernel(
    const bf16t* __restrict__ A, const bf16t* __restrict__ Bt,
    const float* __restrict__ bias, const float* __restrict__ resid,
    void* __restrict__ Cout, int M, int N, int K) {
  __shared__ bf16t As[2 * 128 * 32];
  __shared__ bf16t Bs[2 * 128 * 32];
  const int tid = threadIdx.x;
  const int lane = tid & 63;
  const int wid = tid >> 6;
  const int wr = wid >> 1, wc = wid & 1;
  const int g = lane >> 4, lr = lane & 15;

  const int gy = M >> 7;
  const int nwg = gridDim.x;
  const int chunk = nwg >> 3;
  const int wg = blockIdx.x;
  const int lid = (wg & 7) * chunk + (wg >> 3);
  const int gsz = gy << 3;  // 8 * gy
  const int group = lid / gsz;
  const int rem = lid - group * gsz;
  const int rr = rem >> 3;
  const int cc = (group << 3) + (rem & 7);
  const long brow = (long)rr * 128;
  const long bcol = (long)cc * 128;

  f32x4 acc[4][4];
#pragma unroll
  for (int i = 0; i < 4; i++)
#pragma unroll
    for (int j = 0; j < 4; j++) acc[i][j] = f4zero();

  const int srow = tid >> 2;                       // 0..63 row within round
  const int csrc = (tid & 3) ^ ((tid >> 3) & 3);   // pre-swizzled global 16B-chunk
  const bf16t* gA = &A[(brow + srow) * (long)K + 8 * csrc];
  const bf16t* gB = &Bt[(bcol + srow) * (long)K + 8 * csrc];
  bf16t* lA = As + wid * 512;  // wave-uniform base
  bf16t* lB = Bs + wid * 512;

  const int xsw = ((lr >> 1) & 3) << 3;
  const int ra0 = (4 * g) ^ xsw;
  const int ra1 = (16 + 4 * g) ^ xsw;

  auto stage = [&](int buf, int k0) {
    gld16(gA + k0, lA + buf * 4096);
    gld16(gA + k0 + (long)64 * K, lA + buf * 4096 + 2048);
    gld16(gB + k0, lB + buf * 4096);
    gld16(gB + k0 + (long)64 * K, lB + buf * 4096 + 2048);
  };

  stage(0, 0);
  __syncthreads();

  int cur = 0;
  for (int k0 = 32; k0 < K; k0 += 32) {
    stage(cur ^ 1, k0);
    bf16x8 af[4], bfv[4];
#pragma unroll
    for (int i = 0; i < 4; i++) {
      const bf16t* r = As + cur * 4096 + (wr * 64 + i * 16 + lr) * 32;
      af[i] = ld8(r + ra0, r + ra1);
    }
#pragma unroll
    for (int j = 0; j < 4; j++) {
      const bf16t* c = Bs + cur * 4096 + (wc * 64 + j * 16 + lr) * 32;
      bfv[j] = ld8(c + ra0, c + ra1);
    }
#pragma unroll
    for (int i = 0; i < 4; i++)
#pragma unroll
      for (int j = 0; j < 4; j++) acc[i][j] = mfma16(af[i], bfv[j], acc[i][j]);
    __syncthreads();
    cur ^= 1;
  }
  {
    bf16x8 af[4], bfv[4];
#pragma unroll
    for (int i = 0; i < 4; i++) {
      const bf16t* r = As + cur * 4096 + (wr * 64 + i * 16 + lr) * 32;
      af[i] = ld8(r + ra0, r + ra1);
    }
#pragma unroll
    for (int j = 0; j < 4; j++) {
      const bf16t* c = Bs + cur * 4096 + (wc * 64 + j * 16 + lr) * 32;
      bfv[j] = ld8(c + ra0, c + ra1);
    }
#pragma unroll
    for (int i = 0; i < 4; i++)
#pragma unroll
      for (int j = 0; j < 4; j++) acc[i][j] = mfma16(af[i], bfv[j], acc[i][j]);
  }

#pragma unroll
  for (int j = 0; j < 4; j++) {
    int col = (int)bcol + wc * 64 + j * 16 + lr;
    float bval = bias ? bias[col] : 0.f;
#pragma unroll
    for (int i = 0; i < 4; i++) {
      long row0 = brow + wr * 64 + i * 16 + 4 * g;
#pragma unroll
      for (int r2 = 0; r2 < 4; r2++) {
        long row = row0 + r2;
        float v = acc[i][j][r2] + bval;
        if (EPI == 0) {
          ((bf16t*)Cout)[row * N + col] = (bf16t)v;
        } else if (EPI == 1) {
          ((bf16t*)Cout)[row * N + col] = (bf16t)fmaxf(v, 0.f);
        } else {
          ((float*)Cout)[row * N + col] = v + resid[row * N + col];
        }
      }
    }
  }
}

// ---------------- flash attention, swapped-QK^T in-register softmax ----------------
__global__ __launch_bounds__(256) void attn_kernel(const bf16t* __restrict__ qkv,
                                                   const bf16t* __restrict__ vT,
                                                   bf16t* __restrict__ o) {
  const int bh = blockIdx.x;  // 0..127
  const int b = bh >> 4, h = bh & 15;
  const int qt = blockIdx.y;  // 0..15
  const int tid = threadIdx.x;
  const int lane = tid & 63;
  const int w = tid >> 6;
  const int g = lane >> 4, lr = lane & 15;

  __shared__ bf16t Qs[64 * 64];
  __shared__ bf16t Ks[2][64 * 64];
  __shared__ bf16t Vs[2][64 * 64];

  const long rowbase = (long)b * TT;
  const long qrow0 = rowbase + (long)qt * 64;

  const int srow_in_call = w * 8 + (lane >> 3);          // 0..31
  const int schunk = (lane & 7) ^ ((lane >> 3) & 7);     // swizzled source chunk
  const int soff = 8 * schunk;                           // elem offset in 64-elem row

  const bf16t* qsrc = &qkv[(qrow0 + srow_in_call) * 3072 + h * 64 + soff];
  const bf16t* ksrc = &qkv[(rowbase + srow_in_call) * 3072 + 1024 + h * 64 + soff];
  const bf16t* vsrc = &vT[((long)bh * 64 + srow_in_call) * 1024 + soff];
  bf16t* ldst = (bf16t*)((w * 8) * 64);  // numeric wave base offset (elems)

  auto stageQ = [&]() {
    gld16(qsrc, Qs + (size_t)ldst);
    gld16(qsrc + (long)32 * 3072, Qs + (size_t)ldst + 32 * 64);
  };
  auto stageK = [&](int buf, int kt) {
    const bf16t* s = ksrc + (long)kt * 64 * 3072;
    gld16(s, Ks[buf] + (size_t)ldst);
    gld16(s + (long)32 * 3072, Ks[buf] + (size_t)ldst + 32 * 64);
  };
  auto stageV = [&](int buf, int kt) {
    const bf16t* s = vsrc + kt * 64;
    gld16(s, Vs[buf] + (size_t)ldst);
    gld16(s + (long)32 * 1024, Vs[buf] + (size_t)ldst + 32 * 64);
  };

  stageQ();
  stageK(0, 0);
  stageV(0, 0);
  __syncthreads();  // vmcnt(0) drained: tile 0 + Q ready

  const int swk = (lr & 7) << 3;
  const int o0 = (4 * g) ^ swk, o1 = (16 + 4 * g) ^ swk;
  const int o2 = (32 + 4 * g) ^ swk, o3 = (48 + 4 * g) ^ swk;

  const bf16t* qrow = Qs + (w * 16 + lr) * 64;
  const bf16x8 qb_lo = ld8(qrow + o0, qrow + o1);  // d 0..31
  const bf16x8 qb_hi = ld8(qrow + o2, qrow + o3);  // d 32..63

  f32x4 acc_o[4];
#pragma unroll
  for (int j = 0; j < 4; j++) acc_o[j] = f4zero();
  float mrun = -1e30f, lrun = 0.f;  // stats for q = w*16 + lr (lr-domain)

  int cur = 0;
  for (int kt = 0; kt < 16; ++kt) {
    if (kt < 15) {
      stageK(cur ^ 1, kt + 1);
      stageV(cur ^ 1, kt + 1);
    }

    // S^T = K * Q^T : s[jt] holds S[k=jt*16+4g+r][q=lr]
    f32x4 s[4];
#pragma unroll
    for (int jt = 0; jt < 4; jt++) {
      const bf16t* krow = Ks[cur] + (jt * 16 + lr) * 64;
      bf16x8 ka_lo = ld8(krow + o0, krow + o1);
      bf16x8 ka_hi = ld8(krow + o2, krow + o3);
      f32x4 t = f4zero();
      t = mfma16(ka_lo, qb_lo, t);
      t = mfma16(ka_hi, qb_hi, t);
      s[jt] = t;
    }

#pragma unroll
    for (int jt = 0; jt < 4; jt++)
#pragma unroll
      for (int r = 0; r < 4; r++) s[jt][r] *= 0.125f;

    f32x4 mv = vmax4(vmax4(s[0], s[1]), vmax4(s[2], s[3]));
    float tm = fmaxf(fmaxf(mv[0], mv[1]), fmaxf(mv[2], mv[3]));
    tm = fmaxf(tm, __shfl_xor(tm, 16, 64));
    tm = fmaxf(tm, __shfl_xor(tm, 32, 64));

    float mnew = fmaxf(mrun, tm);
    float corr = __expf(mrun - mnew);
    mrun = mnew;

    f32x4 sv = f4zero();
#pragma unroll
    for (int jt = 0; jt < 4; jt++)
#pragma unroll
      for (int r = 0; r < 4; r++) {
        float pv = __expf(s[jt][r] - mnew);
        s[jt][r] = pv;
        sv[r] += pv;
      }
    float tsum = sv[0] + sv[1] + sv[2] + sv[3];
    tsum += __shfl_xor(tsum, 16, 64);
    tsum += __shfl_xor(tsum, 32, 64);
    lrun = lrun * corr + tsum;

#pragma unroll
    for (int r = 0; r < 4; r++) {
      float cq = __shfl(corr, 20 * g + r, 64);
#pragma unroll
      for (int dt = 0; dt < 4; dt++) acc_o[dt][r] *= cq;
    }

    bf16x8 pa0, pa1;
#pragma unroll
    for (int r = 0; r < 4; r++) {
      pa0[r] = (bf16t)s[0][r];
      pa0[r + 4] = (bf16t)s[1][r];
      pa1[r] = (bf16t)s[2][r];
      pa1[r + 4] = (bf16t)s[3][r];
    }

#pragma unroll
    for (int dt = 0; dt < 4; dt++) {
      const bf16t* vrow = Vs[cur] + (dt * 16 + lr) * 64;
      bf16x8 vb_lo = ld8(vrow + o0, vrow + o1);
      bf16x8 vb_hi = ld8(vrow + o2, vrow + o3);
      acc_o[dt] = mfma16(pa0, vb_lo, acc_o[dt]);
      acc_o[dt] = mfma16(pa1, vb_hi, acc_o[dt]);
    }

    __syncthreads();  // next tile staged + guards buffer reuse
    cur ^= 1;
  }

  float inv = 1.0f / lrun;
#pragma unroll
  for (int r = 0; r < 4; r++) {
    float iq = __shfl(inv, 20 * g + r, 64);
    long row = qrow0 + w * 16 + 4 * g + r;
#pragma unroll
    for (int dt = 0; dt < 4; dt++) {
      o[row * (long)DM + h * 64 + dt * 16 + lr] = (bf16t)(acc_o[dt][r] * iq);
    }
  }
}

// ---------------- LayerNorm: x[row][1024] f32 -> bf16 out and/or f32 out ----------------
__global__ __launch_bounds__(256) void ln_kernel(const float* __restrict__ x,
                                                 const float* __restrict__ gamma,
                                                 const float* __restrict__ beta,
                                                 bf16t* __restrict__ out_bf,
                                                 float* __restrict__ out_f32) {
  const long row = blockIdx.x;
  const int tid = threadIdx.x;
  const float* xr = x + row * DM;
  f32x4 v = *(const f32x4*)&xr[tid * 4];
  float s = v[0] + v[1] + v[2] + v[3];
  float ss = v[0] * v[0] + v[1] * v[1] + v[2] * v[2] + v[3] * v[3];
#pragma unroll
  for (int m = 1; m < 64; m <<= 1) {
    s += __shfl_xor(s, m, 64);
    ss += __shfl_xor(ss, m, 64);
  }
  __shared__ float red[8];
  const int w = tid >> 6, lane = tid & 63;
  if (lane == 0) {
    red[w] = s;
    red[4 + w] = ss;
  }
  __syncthreads();
  s = red[0] + red[1] + red[2] + red[3];
  ss = red[4] + red[5] + red[6] + red[7];
  float mean = s * (1.f / DM);
  float var = ss * (1.f / DM) - mean * mean;
  float inv = rsqrtf(var + 1e-5f);
  f32x4 ga = *(const f32x4*)&gamma[tid * 4];
  f32x4 be = *(const f32x4*)&beta[tid * 4];
  bf16x4 ob;
  f32x4 of;
#pragma unroll
  for (int c = 0; c < 4; c++) {
    float y = (v[c] - mean) * inv * ga[c] + be[c];
    ob[c] = (bf16t)y;
    of[c] = y;
  }
  long base = row * DM + tid * 4;
  if (out_bf) *(bf16x4*)&out_bf[base] = ob;
  if (out_f32) *(f32x4*)&out_f32[base] = of;
}

extern "C" void kernel_launch(void* const* d_in, const int* in_sizes, int n_in,
                              void* d_out, int out_size, void* d_ws, size_t ws_size,
                              hipStream_t stream) {
  const float* z = (const float*)d_in[0];
  const float* Wq = (const float*)d_in[1];
  const float* bq = (const float*)d_in[2];
  const float* Wk = (const float*)d_in[3];
  const float* bk = (const float*)d_in[4];
  const float* Wv = (const float*)d_in[5];
  const float* bv = (const float*)d_in[6];
  const float* Wo = (const float*)d_in[7];
  const float* bo = (const float*)d_in[8];
  const float* W1 = (const float*)d_in[9];
  const float* b1 = (const float*)d_in[10];
  const float* W2 = (const float*)d_in[11];
  const float* b2 = (const float*)d_in[12];
  const float* g1 = (const float*)d_in[13];
  const float* be1 = (const float*)d_in[14];
  const float* g2 = (const float*)d_in[15];
  const float* be2 = (const float*)d_in[16];

  char* p = (char*)d_ws;
  auto alloc = [&](size_t bytes) {
    char* r = p;
    p += (bytes + 255) & ~(size_t)255;
    return r;
  };
  bf16t* wqkvT = (bf16t*)alloc((size_t)3072 * 1024 * 2);  // [3072][1024]
  float* bqkv = (float*)alloc((size_t)3072 * 4);
  bf16t* woT = (bf16t*)alloc((size_t)1024 * 1024 * 2);    // [1024][1024]
  bf16t* w1T = (bf16t*)alloc((size_t)4096 * 1024 * 2);    // [4096][1024]
  bf16t* w2T = (bf16t*)alloc((size_t)1024 * 4096 * 2);    // [1024][4096]
  bf16t* act = (bf16t*)alloc((size_t)BT * 1024 * 2);
  bf16t* obuf = (bf16t*)alloc((size_t)BT * 1024 * 2);
  bf16t* big = (bf16t*)alloc((size_t)BT * 4096 * 2);  // qkv[M][3072] / ffn-h[M][4096]
  float* tbuf = (float*)alloc((size_t)BT * 1024 * 4);
  float* residf = (float*)alloc((size_t)BT * 1024 * 4);
  // vT aliases tbuf (disjoint lifetimes)
  bf16t* vT = (bf16t*)tbuf;  // [128][64][1024] = 16 MB

  pack_qkv_t_kernel<<<dim3(48, 16), dim3(256), 0, stream>>>(Wq, Wk, Wv, wqkvT);
  pack_bias_kernel<<<dim3(12), dim3(256), 0, stream>>>(bq, bk, bv, bqkv);
  tcvt_kernel<<<dim3(16, 16), dim3(256), 0, stream>>>(Wo, woT, 1024, 1024);
  tcvt_kernel<<<dim3(64, 16), dim3(256), 0, stream>>>(W1, w1T, 1024, 4096);
  tcvt_kernel<<<dim3(16, 64), dim3(256), 0, stream>>>(W2, w2T, 4096, 1024);
  cvt_kernel<<<dim3(8192), dim3(256), 0, stream>>>(z, act, (long)BT * 1024);

  for (int iter = 0; iter < 2; ++iter) {
    // QKV projection: grid = (3072/128)*(8192/128) = 24*64 = 1536
    gemm_kernel<0><<<dim3(1536), dim3(256), 0, stream>>>(
        act, wqkvT, bqkv, (const float*)nullptr, (void*)big, BT, 3072, 1024);
    // V transpose to [bh][d][t]
    vtrans_kernel<<<dim3(128, 16), dim3(256), 0, stream>>>(big, vT);
    // attention
    attn_kernel<<<dim3(128, 16), dim3(256), 0, stream>>>(big, vT, obuf);
    // O-projection + residual: grid = 8*64 = 512
    const float* rsrc = (iter == 0) ? z : residf;
    gemm_kernel<2><<<dim3(512), dim3(256), 0, stream>>>(
        obuf, woT, bo, rsrc, (void*)tbuf, BT, 1024, 1024);
    if (iter == 1) {
      ln_kernel<<<dim3(8192), dim3(256), 0, stream>>>(tbuf, g1, be1, (bf16t*)nullptr,
                                                      (float*)d_out);
      break;
    }
    ln_kernel<<<dim3(8192), dim3(256), 0, stream>>>(tbuf, g1, be1, act, residf);
    // FFN: grid = 32*64 = 2048 ; 8*64 = 512
    gemm_kernel<1><<<dim3(2048), dim3(256), 0, stream>>>(
        act, w1T, b1, (const float*)nullptr, (void*)big, BT, 4096, 1024);
    gemm_kernel<2><<<dim3(512), dim3(256), 0, stream>>>(
        big, w2T, b2, residf, (void*)tbuf, BT, 1024, 4096);
    ln_kernel<<<dim3(8192), dim3(256), 0, stream>>>(tbuf, g2, be2, act, residf);
  }
}